// Round 6
// baseline (466.653 us; speedup 1.0000x reference)
//
#include <hip/hip_runtime.h>
#include <hip/hip_bf16.h>

typedef unsigned short u16;
typedef float v4f __attribute__((ext_vector_type(4)));
typedef __bf16 v8bf __attribute__((ext_vector_type(8)));
typedef unsigned short v4u __attribute__((ext_vector_type(4)));
typedef unsigned short v8u __attribute__((ext_vector_type(8)));

#define EMB 1024
#define TOK 4096
#define LSEQ 2048
#define NBATCH 2
#define SCALING 0.015625f
#define LN_EPS 1e-5f

template <int V> struct ic { static constexpr int v = V; };

__device__ __forceinline__ float bf2f(u16 u) {
  unsigned int i = ((unsigned int)u) << 16;
  return __builtin_bit_cast(float, i);
}
__device__ __forceinline__ u16 f2bf(float f) {
  __hip_bfloat16 h = __float2bfloat16(f);  // RNE
  return __builtin_bit_cast(u16, h);
}
__device__ __forceinline__ v8bf load8(const u16* p) {
  return *reinterpret_cast<const v8bf*>(p);
}
__device__ __forceinline__ v4f mfma16(v8bf a, v8bf b, v4f c) {
  return __builtin_amdgcn_mfma_f32_16x16x32_bf16(a, b, c, 0, 0, 0);
}
// async global->LDS, 16B/lane; LDS dest = wave-uniform base + lane*16
__device__ __forceinline__ void gload16(const u16* g, u16* l) {
  __builtin_amdgcn_global_load_lds(
      (const __attribute__((address_space(1))) void*)g,
      (__attribute__((address_space(3))) void*)l, 16, 0, 0);
}
// counted vmcnt wait: allow N loads to remain in flight (T4). "memory"
// clobber also pins compiler ordering of LDS reads / gload_lds around it.
template <int N>
__device__ __forceinline__ void waitcnt_vm() {
  if constexpr (N == 0) asm volatile("s_waitcnt vmcnt(0)" ::: "memory");
  else if constexpr (N == 2) asm volatile("s_waitcnt vmcnt(2)" ::: "memory");
  else if constexpr (N == 4) asm volatile("s_waitcnt vmcnt(4)" ::: "memory");
  else if constexpr (N == 6) asm volatile("s_waitcnt vmcnt(6)" ::: "memory");
  else if constexpr (N == 8) asm volatile("s_waitcnt vmcnt(8)" ::: "memory");
}
// fast GELU (tanh form, ~9 VALU ops, no divergence): max |err| ~3e-4
__device__ __forceinline__ float gelu_fast(float v) {
  float u = v * (0.7978845608f + 0.0356774081f * v * v);
  return v / (1.0f + __expf(-2.0f * u));
}

// ---------------- fp32 -> bf16 weight conversion -------------------------
__global__ __launch_bounds__(256) void cvt_kernel(
    const float* __restrict__ in, u16* __restrict__ out) {
  size_t i = ((size_t)blockIdx.x * 256 + threadIdx.x) * 8;
  v4f a = *reinterpret_cast<const v4f*>(in + i);
  v4f b = *reinterpret_cast<const v4f*>(in + i + 4);
  v8u r;
#pragma unroll
  for (int j = 0; j < 4; j++) { r[j] = f2bf(a[j]); r[4 + j] = f2bf(b[j]); }
  *reinterpret_cast<v8u*>(out + i) = r;
}

// ---------------- split-K reduce: out += p0(bf16) ------------------------
__global__ __launch_bounds__(256) void addred_kernel(
    float* __restrict__ out, const u16* __restrict__ p0) {
  size_t i = ((size_t)blockIdx.x * 256 + threadIdx.x) * 8;
  v4f a0 = *reinterpret_cast<const v4f*>(out + i);
  v4f a1 = *reinterpret_cast<const v4f*>(out + i + 4);
  v8u pp = *reinterpret_cast<const v8u*>(p0 + i);
#pragma unroll
  for (int j = 0; j < 4; j++) {
    a0[j] += bf2f(pp[j]);
    a1[j] += bf2f(pp[4 + j]);
  }
  *reinterpret_cast<v4f*>(out + i) = a0;
  *reinterpret_cast<v4f*>(out + i + 4) = a1;
}

// ---------------- LayerNorm: MODE 0 bf16-in, MODE 1 fp32-in -> bf16 out --
template <int MODE>
__global__ __launch_bounds__(256) void ln_kernel(
    const void* __restrict__ xin, const float* __restrict__ w,
    const float* __restrict__ b, u16* __restrict__ y) {
  int t = blockIdx.x, tid = threadIdx.x;
  float v[4];
  if (MODE == 0) {
    v4u raw = *reinterpret_cast<const v4u*>((const u16*)xin + (size_t)t * EMB + tid * 4);
#pragma unroll
    for (int j = 0; j < 4; j++) v[j] = bf2f(raw[j]);
  } else {
    v4f raw = *reinterpret_cast<const v4f*>((const float*)xin + (size_t)t * EMB + tid * 4);
#pragma unroll
    for (int j = 0; j < 4; j++) v[j] = raw[j];
  }
  float s = v[0] + v[1] + v[2] + v[3];
  float ss = v[0] * v[0] + v[1] * v[1] + v[2] * v[2] + v[3] * v[3];
#pragma unroll
  for (int off = 32; off >= 1; off >>= 1) {
    s += __shfl_xor(s, off);
    ss += __shfl_xor(ss, off);
  }
  __shared__ float sm[4], sq[4];
  if ((tid & 63) == 0) { sm[tid >> 6] = s; sq[tid >> 6] = ss; }
  __syncthreads();
  s = sm[0] + sm[1] + sm[2] + sm[3];
  ss = sq[0] + sq[1] + sq[2] + sq[3];
  float mu = s * (1.0f / EMB);
  float var = ss * (1.0f / EMB) - mu * mu;
  float rstd = rsqrtf(var + LN_EPS);
  v4f wv = *reinterpret_cast<const v4f*>(w + tid * 4);
  v4f bv = *reinterpret_cast<const v4f*>(b + tid * 4);
  v4u out;
#pragma unroll
  for (int j = 0; j < 4; j++) out[j] = f2bf((v[j] - mu) * rstd * wv[j] + bv[j]);
  *reinterpret_cast<v4u*>(y + (size_t)t * EMB + tid * 4) = out;
}

// ---------------- small GEMM engine (256 thr, <64,128>): out GEMM only ---
// mode 1: out_bf = bf16(res_f32 + v)
template <int BM, int BN>
__global__ __launch_bounds__(256) void gemm_db_kernel(
    const u16* __restrict__ A, const u16* __restrict__ W,
    const float* __restrict__ bias, int K, int Nout, int mode,
    u16* __restrict__ out_bf, float* __restrict__ out_f,
    const float* __restrict__ res_f32, const u16* __restrict__ res_bf) {
  constexpr int NJ = BM * BN / 4096;   // col fragments per wave
  constexpr int CWV = 4 / (BM / 64);   // col-waves
  __shared__ alignas(16) u16 lA[2][BM * 32];
  __shared__ alignas(16) u16 lB[2][BN * 32];

  int tid = threadIdx.x;
  int lane = tid & 63, wid = tid >> 6;
  int quad = lane >> 4, l16 = lane & 15;
  int row0 = blockIdx.x * BM;
  int col0 = blockIdx.y * BN;
  int rw = (wid / CWV) * 64;
  int cw = (wid % CWV) * (BN / CWV);

  v4f zero = {0.f, 0.f, 0.f, 0.f};
  v4f acc[4][NJ];
#pragma unroll
  for (int i = 0; i < 4; i++)
#pragma unroll
    for (int j = 0; j < NJ; j++) acc[i][j] = zero;

  int wbase8 = (tid & 192) * 8;

  auto stage = [&](int buf, int k0) {
    const u16* Ab = A + (size_t)row0 * K + k0;
    const u16* Wb = W + (size_t)col0 * K + k0;
#pragma unroll
    for (int n = 0; n < BM / 64; n++) {
      int slot = n * 256 + tid;
      int seg = slot / BM, r = slot & (BM - 1);
      gload16(Ab + (size_t)r * K + seg * 8, &lA[buf][n * 2048 + wbase8]);
    }
#pragma unroll
    for (int n = 0; n < BN / 64; n++) {
      int slot = n * 256 + tid;
      int seg = slot / BN, r = slot & (BN - 1);
      gload16(Wb + (size_t)r * K + seg * 8, &lB[buf][n * 2048 + wbase8]);
    }
  };

  stage(0, 0);
  int buf = 0;
  for (int k0 = 0; k0 < K; k0 += 32) {
    __syncthreads();
    if (k0 + 32 < K) stage(buf ^ 1, k0 + 32);

    v8bf af[4], bfr[NJ];
#pragma unroll
    for (int i = 0; i < 4; i++)
      af[i] = load8(&lA[buf][(quad * BM + rw + i * 16 + l16) * 8]);
#pragma unroll
    for (int j = 0; j < NJ; j++)
      bfr[j] = load8(&lB[buf][(quad * BN + cw + j * 16 + l16) * 8]);
#pragma unroll
    for (int i = 0; i < 4; i++)
#pragma unroll
      for (int j = 0; j < NJ; j++)
        acc[i][j] = mfma16(af[i], bfr[j], acc[i][j]);
    buf ^= 1;
  }

#pragma unroll
  for (int i = 0; i < 4; i++) {
    int rbase = row0 + rw + i * 16 + quad * 4;
#pragma unroll
    for (int j = 0; j < NJ; j++) {
      int c = col0 + cw + j * 16 + l16;
      float bv = bias[c];
#pragma unroll
      for (int r = 0; r < 4; r++) {
        int tok = rbase + r;
        float v = acc[i][j][r] + bv;
        size_t idx = (size_t)tok * Nout + c;
        if (mode == 1) {
          out_bf[idx] = f2bf(res_f32[idx] + v);
        } else if (mode == 3) {
          out_f[idx] = bf2f(res_bf[idx]) + v;
        }
      }
    }
  }
}

// ---------------- 8-phase 256^2 GEMM engine (T3+T4+T5 port) --------------
// R15: R1/R3/R4 falsifications showed ~110 µs invariant across occupancy,
// staged bytes, and coarse pipelining; R5's coalesced staging gave +36%
// but left 3-4x headroom vs every pipe floor (MFMA 155cyc, LDS 830cyc,
// L2 ~500cyc per K-step vs 2900 actual). Residual = 2-phase serialization
// (guide m233: 72% of 2-phase time). Port of the m201 8-phase template:
// BK=64, 8 waves (2Mx4N), per-wave C 128x64, 4 phases per K-tile each
// {ds_read one subtile || issue 1 half-tile stage -> BAR -> setprio(1) ->
// 16 MFMA -> setprio(0) -> counted vmcnt -> BAR}; vmcnt(4) (never 0
// in-loop, m218) at end of ph0/ph1/ph3; last tile peeled with one drain.
// LDS 128KB: 2 buf x 2 PHASE-ALIGNED groups per operand:
//   A group g = rows {g*64..g*64+63} u {128+g*64..} (what ALL waves read
//   in quadrant qa=g), B group g = col stripes [cw+g*32, cw+g*32+32) --
//   so each phase consumes exactly one group and the staggered vmcnt
//   counting is valid for every wave.
// Stage: slot p -> row ri=p>>3, seg sp=p&7, logical seg = sp^(ri&7)
// (rule-21 both-sides swizzle; lanes 0..7 = one 128B line, coalesced).
// Read:  phys seg = s^(ri&7) -> 2-way bank conflict only (free, m136).
// mode 2: out_bf = gelu_fast(v)   mode 4: qkv head-major scatter
// mode 5: split-K=2 over blockIdx.z (z0 -> bf16 raw partial, z1 -> fp32
//         v+bias+res_bf; addred adds).
template <int BM, int BN>
__global__ __launch_bounds__(512, 2) void gemm8_kernel(
    const u16* __restrict__ A, const u16* __restrict__ W,
    const float* __restrict__ bias, int K, int Nout, int mode,
    u16* __restrict__ out_bf, float* __restrict__ out_f,
    const u16* __restrict__ res_bf) {
  static_assert(BM == 256 && BN == 256, "geometry fixed at 256^2");
  __shared__ alignas(16) u16 lA[2][2][8192];
  __shared__ alignas(16) u16 lB[2][2][8192];

  int tid = threadIdx.x;
  int lane = tid & 63, wid = tid >> 6;
  int quad = lane >> 4, l16 = lane & 15;
  int rwh = wid >> 2;            // wave row-half (rows rwh*128 ..)
  int cwq = wid & 3;             // wave col quarter (cols cwq*64 ..)
  int row0 = blockIdx.x * BM, col0 = blockIdx.y * BN;

  int kbeg = 0, kend = K;
  if (mode == 5) { int h = K >> 1; kbeg = blockIdx.z * h; kend = kbeg + h; }
  int nt = (kend - kbeg) >> 6;   // K-tiles of 64

  v4f zero = {0.f, 0.f, 0.f, 0.f};
  v4f acc[8][4];
#pragma unroll
  for (int i = 0; i < 8; i++)
#pragma unroll
    for (int j = 0; j < 4; j++) acc[i][j] = zero;

  int wslot = tid & 448;  // wid*64: wave-uniform LDS slot base

  // ---- staging: one group = 1024 slots of 16B = 2 gload16/thread ----
  auto stA = [&](int buf, int g, int kt) {
    int koff = kbeg + kt * 64;
#pragma unroll
    for (int n = 0; n < 2; n++) {
      int p = n * 512 + tid;
      int ri = p >> 3, sp = p & 7;
      int row = ((ri >> 6) << 7) | (g << 6) | (ri & 63);
      int sl = sp ^ (ri & 7);
      gload16(A + (size_t)(row0 + row) * K + koff + sl * 8,
              &lA[buf][g][(n * 512 + wslot) * 8]);
    }
  };
  auto stB = [&](int buf, int g, int kt) {
    int koff = kbeg + kt * 64;
#pragma unroll
    for (int n = 0; n < 2; n++) {
      int p = n * 512 + tid;
      int ci = p >> 3, sp = p & 7;
      int col = ((ci >> 5) << 6) | (g << 5) | (ci & 31);
      int sl = sp ^ (ci & 7);
      gload16(W + (size_t)(col0 + col) * K + koff + sl * 8,
              &lB[buf][g][(n * 512 + wslot) * 8]);
    }
  };

  // ---- register subtile reads ----
  auto rdA = [&](v8bf (&af)[4][2], int buf, int g) {
#pragma unroll
    for (int i = 0; i < 4; i++) {
      int ri = (rwh << 6) + i * 16 + l16;
      int rs = ri * 8, rx = ri & 7;
#pragma unroll
      for (int kk = 0; kk < 2; kk++)
        af[i][kk] = load8(&lA[buf][g][(rs + ((kk * 4 + quad) ^ rx)) * 8]);
    }
  };
  auto rdB = [&](v8bf (&bf)[2][2], int buf, int g) {
#pragma unroll
    for (int j = 0; j < 2; j++) {
      int ci = (cwq << 5) + j * 16 + l16;
      int rs = ci * 8, rx = ci & 7;
#pragma unroll
      for (int kk = 0; kk < 2; kk++)
        bf[j][kk] = load8(&lB[buf][g][(rs + ((kk * 4 + quad) ^ rx)) * 8]);
    }
  };
  // ---- one C-quadrant x K=64: 16 MFMA (static acc indices via ic<>) ----
  auto mm = [&](auto QA, auto QB, v8bf (&af)[4][2], v8bf (&bf)[2][2]) {
    constexpr int qa = decltype(QA)::v, qb = decltype(QB)::v;
#pragma unroll
    for (int i = 0; i < 4; i++)
#pragma unroll
      for (int j = 0; j < 2; j++)
#pragma unroll
        for (int kk = 0; kk < 2; kk++)
          acc[qa * 4 + i][qb * 2 + j] =
              mfma16(af[i][kk], bf[j][kk], acc[qa * 4 + i][qb * 2 + j]);
  };

  v8bf af[4][2], b0[2][2], b1[2][2];

  // prologue: tile 0, stage order A0,B0,B1,A1 (matches wait schedule)
  stA(0, 0, 0); stB(0, 0, 0); stB(0, 1, 0); stA(0, 1, 0);
  waitcnt_vm<4>();                 // A0(0), B0(0) landed
  __builtin_amdgcn_s_barrier();

  for (int t = 0; t < nt - 1; ++t) {
    int buf = t & 1, nb = buf ^ 1;
    // ph0: quadrant (0,0)
    rdA(af, buf, 0); rdB(b0, buf, 0);
    stA(nb, 0, t + 1);
    __builtin_amdgcn_s_barrier();
    __builtin_amdgcn_s_setprio(1);
    mm(ic<0>{}, ic<0>{}, af, b0);
    __builtin_amdgcn_s_setprio(0);
    waitcnt_vm<4>();               // B1(t) landed (for ph1)
    __builtin_amdgcn_s_barrier();
    // ph1: quadrant (0,1)
    rdB(b1, buf, 1);
    stB(nb, 0, t + 1);
    __builtin_amdgcn_s_barrier();
    __builtin_amdgcn_s_setprio(1);
    mm(ic<0>{}, ic<1>{}, af, b1);
    __builtin_amdgcn_s_setprio(0);
    waitcnt_vm<4>();               // A1(t) landed (for ph2)
    __builtin_amdgcn_s_barrier();
    // ph2: quadrant (1,1)
    rdA(af, buf, 1);
    stB(nb, 1, t + 1);
    __builtin_amdgcn_s_barrier();
    __builtin_amdgcn_s_setprio(1);
    mm(ic<1>{}, ic<1>{}, af, b1);
    __builtin_amdgcn_s_setprio(0);
    __builtin_amdgcn_s_barrier();
    // ph3: quadrant (1,0) — no reads
    stA(nb, 1, t + 1);
    __builtin_amdgcn_s_barrier();
    __builtin_amdgcn_s_setprio(1);
    mm(ic<1>{}, ic<0>{}, af, b0);
    __builtin_amdgcn_s_setprio(0);
    waitcnt_vm<4>();               // A0(t+1), B0(t+1) landed (for next ph0)
    __builtin_amdgcn_s_barrier();
  }
  // peeled final tile: single drain
  waitcnt_vm<0>();
  __builtin_amdgcn_s_barrier();
  {
    int buf = (nt - 1) & 1;
    rdA(af, buf, 0); rdB(b0, buf, 0); rdB(b1, buf, 1);
    mm(ic<0>{}, ic<0>{}, af, b0);
    mm(ic<0>{}, ic<1>{}, af, b1);
    rdA(af, buf, 1);
    mm(ic<1>{}, ic<1>{}, af, b1);
    mm(ic<1>{}, ic<0>{}, af, b0);
  }

  // ---- epilogue (same layout as before: rows m*16, cols mj*16) ----
  int rw = rwh << 7;
  int cw = cwq << 6;
#pragma unroll
  for (int i = 0; i < 8; i++) {
    int rbase = row0 + rw + i * 16 + quad * 4;
#pragma unroll
    for (int j = 0; j < 4; j++) {
      int c = col0 + cw + j * 16 + l16;
      float bv = bias[c];
#pragma unroll
      for (int r = 0; r < 4; r++) {
        int tok = rbase + r;
        float raw = acc[i][j][r];
        float v = raw + bv;
        if (mode == 4) {
          int region = c >> 10;  // 0=q,1=k,2=v
          int cc = c & 1023;
          int hh = cc >> 6, dd = cc & 63;
          int l = tok >> 1, nn = tok & 1;
          size_t hb = (size_t)(nn * 16 + hh);
          if (region == 0) {
            out_bf[(hb * LSEQ + l) * 64 + dd] = f2bf(v * SCALING);
          } else if (region == 1) {
            out_bf[4194304 + (hb * LSEQ + l) * 64 + dd] = f2bf(v);
          } else {
            out_bf[8388608 + (hb * 64 + dd) * LSEQ + l] = f2bf(v);
          }
        } else {
          size_t idx = (size_t)tok * Nout + c;
          if (mode == 2) {
            out_bf[idx] = f2bf(gelu_fast(v));
          } else {  // mode 5: split-K partials
            if (blockIdx.z == 0) {
              out_bf[idx] = f2bf(raw);                  // chunk-0 raw partial
            } else {
              out_f[idx] = v + bf2f(res_bf[idx]);       // chunk-1 + bias + x2
            }
          }
        }
      }
    }
  }
}

// ---------------- Flash attention (no-max softmax, swizzled LDS) ---------
// Inputs head-major: q,k (n,h,l,d) [q pre-scaled], vt (n,h,d,l).
__global__ __launch_bounds__(256) void flash_kernel(
    const u16* __restrict__ qb, const u16* __restrict__ kb,
    const u16* __restrict__ vtb, u16* __restrict__ o) {
  int tid = threadIdx.x;
  int lane = tid & 63, wid = tid >> 6;
  int quad = lane >> 4, l16 = lane & 15;
  int qt = blockIdx.x;
  int nh = blockIdx.y;
  int n = nh >> 4, h = nh & 15;

  __shared__ alignas(16) u16 lK[4096];
  __shared__ alignas(16) u16 lV[4096];
  __shared__ alignas(16) u16 pl[128][72];

  const u16* khead = kb + (size_t)nh * (LSEQ * 64);
  const u16* vhead = vtb + (size_t)nh * (64 * LSEQ);

  v4f zero = {0.f, 0.f, 0.f, 0.f};
  v4f acc_o[2][4];
  float lsum[2][4];
#pragma unroll
  for (int i = 0; i < 2; i++) {
#pragma unroll
    for (int r = 0; r < 4; r++) lsum[i][r] = 0.f;
#pragma unroll
    for (int jd = 0; jd < 4; jd++) acc_o[i][jd] = zero;
  }

  v8bf qf[2][2];
#pragma unroll
  for (int i = 0; i < 2; i++) {
    int lq = qt * 128 + wid * 32 + i * 16 + l16;
#pragma unroll
    for (int kk = 0; kk < 2; kk++)
      qf[i][kk] = load8(qb + ((size_t)nh * LSEQ + lq) * 64 + kk * 32 + quad * 8);
  }

  int swl = l16 & 7;
  int srow = tid >> 3;
  int sseg0 = tid & 7;
  int lbase = (tid & 192) * 8;

  for (int s0 = 0; s0 < LSEQ; s0 += 64) {
#pragma unroll
    for (int p = 0; p < 2; p++) {
      int row = p * 32 + srow;
      int seg = sseg0 ^ (row & 7);
      gload16(khead + (size_t)(s0 + row) * 64 + seg * 8, &lK[p * 2048 + lbase]);
      gload16(vhead + (size_t)row * LSEQ + s0 + seg * 8, &lV[p * 2048 + lbase]);
    }
    __syncthreads();

    v4f sacc[2][4];
#pragma unroll
    for (int i = 0; i < 2; i++)
#pragma unroll
      for (int j = 0; j < 4; j++) sacc[i][j] = zero;
#pragma unroll
    for (int kk = 0; kk < 2; kk++) {
      v8bf kf[4];
#pragma unroll
      for (int j = 0; j < 4; j++) {
        int rl = j * 16 + l16;
        kf[j] = load8(&lK[((rl << 3) + (((kk << 2) + quad) ^ swl)) << 3]);
      }
#pragma unroll
      for (int i = 0; i < 2; i++)
#pragma unroll
        for (int j = 0; j < 4; j++)
          sacc[i][j] = mfma16(qf[i][kk], kf[j], sacc[i][j]);
    }

#pragma unroll
    for (int i = 0; i < 2; i++) {
#pragma unroll
      for (int r = 0; r < 4; r++) {
        float ps = 0.f;
#pragma unroll
        for (int j = 0; j < 4; j++) {
          float p = __expf(fminf(sacc[i][j][r], 60.f));
          ps += p;
          pl[wid * 32 + i * 16 + quad * 4 + r][j * 16 + l16] = f2bf(p);
        }
        lsum[i][r] += ps;
      }
    }

#pragma unroll
    for (int kk = 0; kk < 2; kk++) {
      v8bf pf[2], vf[4];
#pragma unroll
      for (int i = 0; i < 2; i++)
        pf[i] = load8(&pl[wid * 32 + i * 16 + l16][kk * 32 + quad * 8]);
#pragma unroll
      for (int jd = 0; jd < 4; jd++) {
        int dl = jd * 16 + l16;
        vf[jd] = load8(&lV[((dl << 3) + (((kk << 2) + quad) ^ swl)) << 3]);
      }
#pragma unroll
      for (int i = 0; i < 2; i++)
#pragma unroll
        for (int jd = 0; jd < 4; jd++)
          acc_o[i][jd] = mfma16(pf[i], vf[jd], acc_o[i][jd]);
    }
    __syncthreads();
  }

#pragma unroll
  for (int i = 0; i < 2; i++) {
#pragma unroll
    for (int r = 0; r < 4; r++) {
      float s = lsum[i][r];
#pragma unroll
      for (int off = 1; off < 16; off <<= 1) s += __shfl_xor(s, off);
      float inv = 1.0f / s;
      int lq = qt * 128 + wid * 32 + i * 16 + quad * 4 + r;
      size_t t = (size_t)lq * NBATCH + n;
#pragma unroll
      for (int jd = 0; jd < 4; jd++)
        o[t * EMB + h * 64 + jd * 16 + l16] = f2bf(acc_o[i][jd][r] * inv);
    }
  }
}

// ---------------- launcher ----------------
extern "C" void kernel_launch(void* const* d_in, const int* in_sizes, int n_in,
                              void* d_out, int out_size, void* d_ws,
                              size_t ws_size, hipStream_t stream) {
  const float* x = (const float*)d_in[0];
  const float* ln1_w = (const float*)d_in[1];
  const float* ln1_b = (const float*)d_in[2];
  const float* in_proj_w = (const float*)d_in[3];
  const float* in_proj_b = (const float*)d_in[4];
  const float* out_w = (const float*)d_in[5];
  const float* out_b = (const float*)d_in[6];
  const float* ln2_w = (const float*)d_in[7];
  const float* ln2_b = (const float*)d_in[8];
  const float* fc_w = (const float*)d_in[9];
  const float* fc_b = (const float*)d_in[10];
  const float* proj_w = (const float*)d_in[11];
  const float* proj_b = (const float*)d_in[12];
  float* out = (float*)d_out;

  char* ws = (char*)d_ws;
  // wbuf [0,8) ; y/o/h [8,40) ; qkv head-major [16,40) ; x2 bf16 [40,48) ;
  // z [48,56).  56 MB peak (known-good budget).
  u16* wbuf = (u16*)(ws + 0);
  u16* y = (u16*)(ws + 8388608);
  u16* qkvh = (u16*)(ws + 16777216);
  u16* o = (u16*)(ws + 8388608);
  u16* hbuf = (u16*)(ws + 8388608);
  u16* x2 = (u16*)(ws + 41943040);
  u16* z = (u16*)(ws + 50331648);

  u16* qb = qkvh;
  u16* kb = qkvh + 4194304;
  u16* vtb = qkvh + 8388608;

  // 1. ln1(x) -> y
  ln_kernel<1><<<TOK, 256, 0, stream>>>((const void*)x, ln1_w, ln1_b, y);
  // 2. qkv = y @ in_proj^T + b, head-major scatter (q scaled). Grid (16,12).
  cvt_kernel<<<1536, 256, 0, stream>>>(in_proj_w, wbuf);
  gemm8_kernel<256, 256><<<dim3(16, 12), 512, 0, stream>>>(
      y, wbuf, in_proj_b, EMB, 3 * EMB, 4, qkvh, nullptr, nullptr);
  // 3. attention -> o
  flash_kernel<<<dim3(16, 32), 256, 0, stream>>>(qb, kb, vtb, o);
  // 4. x2 = bf16(x + o @ out_w^T + out_b). Small GEMM, unchanged.
  cvt_kernel<<<512, 256, 0, stream>>>(out_w, wbuf);
  gemm_db_kernel<64, 128><<<dim3(64, 8), 256, 0, stream>>>(
      o, wbuf, out_b, EMB, EMB, 1, x2, nullptr, x, nullptr);
  // 5. ln2(x2) -> z
  ln_kernel<0><<<TOK, 256, 0, stream>>>((const void*)x2, ln2_w, ln2_b, z);
  // 6. h = gelu_fast(z @ fc_w^T + fc_b). Grid (16,16).
  cvt_kernel<<<2048, 256, 0, stream>>>(fc_w, wbuf);
  gemm8_kernel<256, 256><<<dim3(16, 16), 512, 0, stream>>>(
      z, wbuf, fc_b, EMB, 4 * EMB, 2, hbuf, nullptr, nullptr);
  // 7. out = x2 + h @ proj_w^T + proj_b. 256^2 split-K=2, grid (16,4,2) =
  //    128 blocks (per-block time governs; half-machine acceptable).
  //    Chunk0 -> bf16 partial in z; chunk1 (+bias+x2) -> fp32 d_out;
  //    addred does out += p0.
  cvt_kernel<<<2048, 256, 0, stream>>>(proj_w, wbuf);
  gemm8_kernel<256, 256><<<dim3(16, 4, 2), 512, 0, stream>>>(
      hbuf, wbuf, proj_b, 4 * EMB, EMB, 5, z, out, x2);
  addred_kernel<<<2048, 256, 0, stream>>>(out, z);
}

// Round 8
// 427.356 us; speedup vs baseline: 1.0920x; 1.0920x over previous
//
#include <hip/hip_runtime.h>
#include <hip/hip_bf16.h>

typedef unsigned short u16;
typedef float v4f __attribute__((ext_vector_type(4)));
typedef __bf16 v8bf __attribute__((ext_vector_type(8)));
typedef unsigned short v4u __attribute__((ext_vector_type(4)));
typedef unsigned short v8u __attribute__((ext_vector_type(8)));

#define EMB 1024
#define TOK 4096
#define LSEQ 2048
#define NBATCH 2
#define SCALING 0.015625f
#define LN_EPS 1e-5f

template <int V> struct ic { static constexpr int v = V; };

__device__ __forceinline__ float bf2f(u16 u) {
  unsigned int i = ((unsigned int)u) << 16;
  return __builtin_bit_cast(float, i);
}
__device__ __forceinline__ u16 f2bf(float f) {
  __hip_bfloat16 h = __float2bfloat16(f);  // RNE
  return __builtin_bit_cast(u16, h);
}
__device__ __forceinline__ v8bf load8(const u16* p) {
  return *reinterpret_cast<const v8bf*>(p);
}
__device__ __forceinline__ v4f mfma16(v8bf a, v8bf b, v4f c) {
  return __builtin_amdgcn_mfma_f32_16x16x32_bf16(a, b, c, 0, 0, 0);
}
// async global->LDS, 16B/lane; LDS dest = wave-uniform base + lane*16
__device__ __forceinline__ void gload16(const u16* g, u16* l) {
  __builtin_amdgcn_global_load_lds(
      (const __attribute__((address_space(1))) void*)g,
      (__attribute__((address_space(3))) void*)l, 16, 0, 0);
}
// counted vmcnt wait: allow N loads to remain in flight (T4). "memory"
// clobber also pins compiler ordering of LDS reads / gload_lds around it.
template <int N>
__device__ __forceinline__ void waitcnt_vm() {
  if constexpr (N == 0) asm volatile("s_waitcnt vmcnt(0)" ::: "memory");
  else if constexpr (N == 2) asm volatile("s_waitcnt vmcnt(2)" ::: "memory");
  else if constexpr (N == 3) asm volatile("s_waitcnt vmcnt(3)" ::: "memory");
  else if constexpr (N == 4) asm volatile("s_waitcnt vmcnt(4)" ::: "memory");
  else if constexpr (N == 6) asm volatile("s_waitcnt vmcnt(6)" ::: "memory");
  else if constexpr (N == 8) asm volatile("s_waitcnt vmcnt(8)" ::: "memory");
}
// fast GELU (tanh form, ~9 VALU ops, no divergence): max |err| ~3e-4
__device__ __forceinline__ float gelu_fast(float v) {
  float u = v * (0.7978845608f + 0.0356774081f * v * v);
  return v / (1.0f + __expf(-2.0f * u));
}

// ---------------- fp32 -> bf16 weight conversion -------------------------
__global__ __launch_bounds__(256) void cvt_kernel(
    const float* __restrict__ in, u16* __restrict__ out) {
  size_t i = ((size_t)blockIdx.x * 256 + threadIdx.x) * 8;
  v4f a = *reinterpret_cast<const v4f*>(in + i);
  v4f b = *reinterpret_cast<const v4f*>(in + i + 4);
  v8u r;
#pragma unroll
  for (int j = 0; j < 4; j++) { r[j] = f2bf(a[j]); r[4 + j] = f2bf(b[j]); }
  *reinterpret_cast<v8u*>(out + i) = r;
}

// ---------------- split-K reduce: out += p0(bf16) ------------------------
__global__ __launch_bounds__(256) void addred_kernel(
    float* __restrict__ out, const u16* __restrict__ p0) {
  size_t i = ((size_t)blockIdx.x * 256 + threadIdx.x) * 8;
  v4f a0 = *reinterpret_cast<const v4f*>(out + i);
  v4f a1 = *reinterpret_cast<const v4f*>(out + i + 4);
  v8u pp = *reinterpret_cast<const v8u*>(p0 + i);
#pragma unroll
  for (int j = 0; j < 4; j++) {
    a0[j] += bf2f(pp[j]);
    a1[j] += bf2f(pp[4 + j]);
  }
  *reinterpret_cast<v4f*>(out + i) = a0;
  *reinterpret_cast<v4f*>(out + i + 4) = a1;
}

// ---------------- LayerNorm: MODE 0 bf16-in, MODE 1 fp32-in -> bf16 out --
template <int MODE>
__global__ __launch_bounds__(256) void ln_kernel(
    const void* __restrict__ xin, const float* __restrict__ w,
    const float* __restrict__ b, u16* __restrict__ y) {
  int t = blockIdx.x, tid = threadIdx.x;
  float v[4];
  if (MODE == 0) {
    v4u raw = *reinterpret_cast<const v4u*>((const u16*)xin + (size_t)t * EMB + tid * 4);
#pragma unroll
    for (int j = 0; j < 4; j++) v[j] = bf2f(raw[j]);
  } else {
    v4f raw = *reinterpret_cast<const v4f*>((const float*)xin + (size_t)t * EMB + tid * 4);
#pragma unroll
    for (int j = 0; j < 4; j++) v[j] = raw[j];
  }
  float s = v[0] + v[1] + v[2] + v[3];
  float ss = v[0] * v[0] + v[1] * v[1] + v[2] * v[2] + v[3] * v[3];
#pragma unroll
  for (int off = 32; off >= 1; off >>= 1) {
    s += __shfl_xor(s, off);
    ss += __shfl_xor(ss, off);
  }
  __shared__ float sm[4], sq[4];
  if ((tid & 63) == 0) { sm[tid >> 6] = s; sq[tid >> 6] = ss; }
  __syncthreads();
  s = sm[0] + sm[1] + sm[2] + sm[3];
  ss = sq[0] + sq[1] + sq[2] + sq[3];
  float mu = s * (1.0f / EMB);
  float var = ss * (1.0f / EMB) - mu * mu;
  float rstd = rsqrtf(var + LN_EPS);
  v4f wv = *reinterpret_cast<const v4f*>(w + tid * 4);
  v4f bv = *reinterpret_cast<const v4f*>(b + tid * 4);
  v4u out;
#pragma unroll
  for (int j = 0; j < 4; j++) out[j] = f2bf((v[j] - mu) * rstd * wv[j] + bv[j]);
  *reinterpret_cast<v4u*>(y + (size_t)t * EMB + tid * 4) = out;
}

// ---------------- small GEMM engine (256 thr, <64,128>): out GEMM only ---
// mode 1: out_bf = bf16(res_f32 + v)
template <int BM, int BN>
__global__ __launch_bounds__(256) void gemm_db_kernel(
    const u16* __restrict__ A, const u16* __restrict__ W,
    const float* __restrict__ bias, int K, int Nout, int mode,
    u16* __restrict__ out_bf, float* __restrict__ out_f,
    const float* __restrict__ res_f32, const u16* __restrict__ res_bf) {
  constexpr int NJ = BM * BN / 4096;   // col fragments per wave
  constexpr int CWV = 4 / (BM / 64);   // col-waves
  __shared__ alignas(16) u16 lA[2][BM * 32];
  __shared__ alignas(16) u16 lB[2][BN * 32];

  int tid = threadIdx.x;
  int lane = tid & 63, wid = tid >> 6;
  int quad = lane >> 4, l16 = lane & 15;
  int row0 = blockIdx.x * BM;
  int col0 = blockIdx.y * BN;
  int rw = (wid / CWV) * 64;
  int cw = (wid % CWV) * (BN / CWV);

  v4f zero = {0.f, 0.f, 0.f, 0.f};
  v4f acc[4][NJ];
#pragma unroll
  for (int i = 0; i < 4; i++)
#pragma unroll
    for (int j = 0; j < NJ; j++) acc[i][j] = zero;

  int wbase8 = (tid & 192) * 8;

  auto stage = [&](int buf, int k0) {
    const u16* Ab = A + (size_t)row0 * K + k0;
    const u16* Wb = W + (size_t)col0 * K + k0;
#pragma unroll
    for (int n = 0; n < BM / 64; n++) {
      int slot = n * 256 + tid;
      int seg = slot / BM, r = slot & (BM - 1);
      gload16(Ab + (size_t)r * K + seg * 8, &lA[buf][n * 2048 + wbase8]);
    }
#pragma unroll
    for (int n = 0; n < BN / 64; n++) {
      int slot = n * 256 + tid;
      int seg = slot / BN, r = slot & (BN - 1);
      gload16(Wb + (size_t)r * K + seg * 8, &lB[buf][n * 2048 + wbase8]);
    }
  };

  stage(0, 0);
  int buf = 0;
  for (int k0 = 0; k0 < K; k0 += 32) {
    __syncthreads();
    if (k0 + 32 < K) stage(buf ^ 1, k0 + 32);

    v8bf af[4], bfr[NJ];
#pragma unroll
    for (int i = 0; i < 4; i++)
      af[i] = load8(&lA[buf][(quad * BM + rw + i * 16 + l16) * 8]);
#pragma unroll
    for (int j = 0; j < NJ; j++)
      bfr[j] = load8(&lB[buf][(quad * BN + cw + j * 16 + l16) * 8]);
#pragma unroll
    for (int i = 0; i < 4; i++)
#pragma unroll
      for (int j = 0; j < NJ; j++)
        acc[i][j] = mfma16(af[i], bfr[j], acc[i][j]);
    buf ^= 1;
  }

#pragma unroll
  for (int i = 0; i < 4; i++) {
    int rbase = row0 + rw + i * 16 + quad * 4;
#pragma unroll
    for (int j = 0; j < NJ; j++) {
      int c = col0 + cw + j * 16 + l16;
      float bv = bias[c];
#pragma unroll
      for (int r = 0; r < 4; r++) {
        int tok = rbase + r;
        float v = acc[i][j][r] + bv;
        size_t idx = (size_t)tok * Nout + c;
        if (mode == 1) {
          out_bf[idx] = f2bf(res_f32[idx] + v);
        } else if (mode == 3) {
          out_f[idx] = bf2f(res_bf[idx]) + v;
        }
      }
    }
  }
}

// ---------------- 8-phase GEMM engine (T3+T4+T5), BN in {128,256} --------
// R17: R7's BN generalization was correct in mapping/waits but had an LDS
// sizing typo: lB group = (BN/2 cols)x(BK=64)x2B = BN*32 u16, was declared
// BN*16 -> staging overran the array 2x on every dispatch (absmax 3.19).
// One-line fix; schedule identical to R6 (which measured +64%/CU vs R5).
// Per K-tile (BK=64): 4 phases {ds_read subtile || issue 1 group-stage ->
// BAR -> setprio(1) -> MFMA cluster -> setprio(0) -> counted vmcnt -> BAR}.
// Load counts LA=2, LB=BN/128; waits: prologue LA+LB, ph0 2LA, ph1 LA+LB,
// ph3 LA+LB (never 0 in-loop, m218). Phase-aligned groups: A group g =
// rows read in quadrant qa=g; B group g = col sub-halves qb=g. Rule-21
// both-sides swizzle: stage logical seg = sp^(ri&7) (lanes 0..7 = one
// 128B line); read phys seg = s^(ri&7) -> 2-way conflict only (free).
// LDS: 2buf x 2grp x (BM*64 + BN*64) B = 128KB(BN=256)/96KB(BN=128).
// mode 2: out_bf = gelu_fast(v)   mode 4: qkv head-major scatter
// mode 5: split-K=2 over blockIdx.z (z0 -> bf16 raw partial, z1 -> fp32
//         v+bias+res_bf; addred adds).
template <int BM, int BN>
__global__ __launch_bounds__(512, 2) void gemm8_kernel(
    const u16* __restrict__ A, const u16* __restrict__ W,
    const float* __restrict__ bias, int K, int Nout, int mode,
    u16* __restrict__ out_bf, float* __restrict__ out_f,
    const u16* __restrict__ res_bf) {
  static_assert(BM == 256 && (BN == 128 || BN == 256), "geometry");
  constexpr int NJF = BN / 128;        // B col-fragments per wave per group
  constexpr int LB = BN / 128;         // gload16 per thread per B-group
  constexpr int H = BN / 8;            // B group sub-half width (cols)
  __shared__ alignas(16) u16 lA[2][2][8192];
  __shared__ alignas(16) u16 lB[2][2][BN * 32];  // BN*32 u16 = BN*64 B/group

  int tid = threadIdx.x;
  int lane = tid & 63, wid = tid >> 6;
  int quad = lane >> 4, l16 = lane & 15;
  int rwh = wid >> 2;            // wave row-half (rows rwh*128 ..)
  int cwq = wid & 3;             // wave col quarter (cols cwq*(BN/4) ..)
  int row0 = blockIdx.x * BM, col0 = blockIdx.y * BN;

  int kbeg = 0, kend = K;
  if (mode == 5) { int h = K >> 1; kbeg = blockIdx.z * h; kend = kbeg + h; }
  int nt = (kend - kbeg) >> 6;   // K-tiles of 64

  v4f zero = {0.f, 0.f, 0.f, 0.f};
  v4f acc[8][2 * NJF];
#pragma unroll
  for (int i = 0; i < 8; i++)
#pragma unroll
    for (int j = 0; j < 2 * NJF; j++) acc[i][j] = zero;

  int wslot = tid & 448;  // wid*64: wave-uniform LDS slot base

  // ---- staging: A group = 1024 slots of 16B (2/thread); B = 512*LB ----
  auto stA = [&](int buf, int g, int kt) {
    int koff = kbeg + kt * 64;
#pragma unroll
    for (int n = 0; n < 2; n++) {
      int p = n * 512 + tid;
      int ri = p >> 3, sp = p & 7;
      int row = ((ri >> 6) << 7) | (g << 6) | (ri & 63);
      int sl = sp ^ (ri & 7);
      gload16(A + (size_t)(row0 + row) * K + koff + sl * 8,
              &lA[buf][g][(n * 512 + wslot) * 8]);
    }
  };
  auto stB = [&](int buf, int g, int kt) {
    int koff = kbeg + kt * 64;
#pragma unroll
    for (int n = 0; n < LB; n++) {
      int p = n * 512 + tid;
      int ci = p >> 3, sp = p & 7;
      int col = (ci / H) * (2 * H) + g * H + (ci % H);
      int sl = sp ^ (ci & 7);
      gload16(W + (size_t)(col0 + col) * K + koff + sl * 8,
              &lB[buf][g][(n * 512 + wslot) * 8]);
    }
  };

  // ---- register subtile reads ----
  auto rdA = [&](v8bf (&af)[4][2], int buf, int g) {
#pragma unroll
    for (int i = 0; i < 4; i++) {
      int ri = (rwh << 6) + i * 16 + l16;
      int rs = ri * 8, rx = ri & 7;
#pragma unroll
      for (int kk = 0; kk < 2; kk++)
        af[i][kk] = load8(&lA[buf][g][(rs + ((kk * 4 + quad) ^ rx)) * 8]);
    }
  };
  auto rdB = [&](v8bf (&bf)[NJF][2], int buf, int g) {
#pragma unroll
    for (int j = 0; j < NJF; j++) {
      int ci = cwq * H + j * 16 + l16;
      int rs = ci * 8, rx = ci & 7;
#pragma unroll
      for (int kk = 0; kk < 2; kk++)
        bf[j][kk] = load8(&lB[buf][g][(rs + ((kk * 4 + quad) ^ rx)) * 8]);
    }
  };
  // ---- one C-quadrant x K=64 (static acc indices via ic<>) ----
  auto mm = [&](auto QA, auto QB, v8bf (&af)[4][2], v8bf (&bf)[NJF][2]) {
    constexpr int qa = decltype(QA)::v, qb = decltype(QB)::v;
#pragma unroll
    for (int i = 0; i < 4; i++)
#pragma unroll
      for (int j = 0; j < NJF; j++)
#pragma unroll
        for (int kk = 0; kk < 2; kk++)
          acc[qa * 4 + i][qb * NJF + j] =
              mfma16(af[i][kk], bf[j][kk], acc[qa * 4 + i][qb * NJF + j]);
  };

  v8bf af[4][2], b0[NJF][2], b1[NJF][2];

  // prologue: tile 0, stage order A0,B0,B1,A1 (matches wait schedule)
  stA(0, 0, 0); stB(0, 0, 0); stB(0, 1, 0); stA(0, 1, 0);
  waitcnt_vm<2 + LB>();            // A0(0), B0(0) landed
  __builtin_amdgcn_s_barrier();

  for (int t = 0; t < nt - 1; ++t) {
    int buf = t & 1, nb = buf ^ 1;
    // ph0: quadrant (0,0)
    rdA(af, buf, 0); rdB(b0, buf, 0);
    stA(nb, 0, t + 1);
    __builtin_amdgcn_s_barrier();
    __builtin_amdgcn_s_setprio(1);
    mm(ic<0>{}, ic<0>{}, af, b0);
    __builtin_amdgcn_s_setprio(0);
    waitcnt_vm<4>();               // B1(t) landed (leave A1 + A0')
    __builtin_amdgcn_s_barrier();
    // ph1: quadrant (0,1)
    rdB(b1, buf, 1);
    stB(nb, 0, t + 1);
    __builtin_amdgcn_s_barrier();
    __builtin_amdgcn_s_setprio(1);
    mm(ic<0>{}, ic<1>{}, af, b1);
    __builtin_amdgcn_s_setprio(0);
    waitcnt_vm<2 + LB>();          // A1(t) landed (leave A0' + B0')
    __builtin_amdgcn_s_barrier();
    // ph2: quadrant (1,1)
    rdA(af, buf, 1);
    stB(nb, 1, t + 1);
    __builtin_amdgcn_s_barrier();
    __builtin_amdgcn_s_setprio(1);
    mm(ic<1>{}, ic<1>{}, af, b1);
    __builtin_amdgcn_s_setprio(0);
    __builtin_amdgcn_s_barrier();
    // ph3: quadrant (1,0) — no reads
    stA(nb, 1, t + 1);
    __builtin_amdgcn_s_barrier();
    __builtin_amdgcn_s_setprio(1);
    mm(ic<1>{}, ic<0>{}, af, b0);
    __builtin_amdgcn_s_setprio(0);
    waitcnt_vm<2 + LB>();          // A0(t+1), B0(t+1) landed (leave B1'+A1')
    __builtin_amdgcn_s_barrier();
  }
  // peeled final tile: single drain
  waitcnt_vm<0>();
  __builtin_amdgcn_s_barrier();
  {
    int buf = (nt - 1) & 1;
    rdA(af, buf, 0); rdB(b0, buf, 0); rdB(b1, buf, 1);
    mm(ic<0>{}, ic<0>{}, af, b0);
    mm(ic<0>{}, ic<1>{}, af, b1);
    rdA(af, buf, 1);
    mm(ic<1>{}, ic<1>{}, af, b1);
    mm(ic<1>{}, ic<0>{}, af, b0);
  }

  // ---- epilogue ----
  int rw = rwh << 7;
  int cw = cwq * (BN / 4);
#pragma unroll
  for (int i = 0; i < 8; i++) {
    int rbase = row0 + rw + i * 16 + quad * 4;
#pragma unroll
    for (int j = 0; j < 2 * NJF; j++) {
      int c = col0 + cw + j * 16 + l16;
      float bv = bias[c];
#pragma unroll
      for (int r = 0; r < 4; r++) {
        int tok = rbase + r;
        float raw = acc[i][j][r];
        float v = raw + bv;
        if (mode == 4) {
          int region = c >> 10;  // 0=q,1=k,2=v
          int cc = c & 1023;
          int hh = cc >> 6, dd = cc & 63;
          int l = tok >> 1, nn = tok & 1;
          size_t hb = (size_t)(nn * 16 + hh);
          if (region == 0) {
            out_bf[(hb * LSEQ + l) * 64 + dd] = f2bf(v * SCALING);
          } else if (region == 1) {
            out_bf[4194304 + (hb * LSEQ + l) * 64 + dd] = f2bf(v);
          } else {
            out_bf[8388608 + (hb * 64 + dd) * LSEQ + l] = f2bf(v);
          }
        } else {
          size_t idx = (size_t)tok * Nout + c;
          if (mode == 2) {
            out_bf[idx] = f2bf(gelu_fast(v));
          } else {  // mode 5: split-K partials
            if (blockIdx.z == 0) {
              out_bf[idx] = f2bf(raw);                  // chunk-0 raw partial
            } else {
              out_f[idx] = v + bf2f(res_bf[idx]);       // chunk-1 + bias + x2
            }
          }
        }
      }
    }
  }
}

// ---------------- Flash attention (no-max softmax, swizzled LDS) ---------
// Inputs head-major: q,k (n,h,l,d) [q pre-scaled], vt (n,h,d,l).
__global__ __launch_bounds__(256) void flash_kernel(
    const u16* __restrict__ qb, const u16* __restrict__ kb,
    const u16* __restrict__ vtb, u16* __restrict__ o) {
  int tid = threadIdx.x;
  int lane = tid & 63, wid = tid >> 6;
  int quad = lane >> 4, l16 = lane & 15;
  int qt = blockIdx.x;
  int nh = blockIdx.y;
  int n = nh >> 4, h = nh & 15;

  __shared__ alignas(16) u16 lK[4096];
  __shared__ alignas(16) u16 lV[4096];
  __shared__ alignas(16) u16 pl[128][72];

  const u16* khead = kb + (size_t)nh * (LSEQ * 64);
  const u16* vhead = vtb + (size_t)nh * (64 * LSEQ);

  v4f zero = {0.f, 0.f, 0.f, 0.f};
  v4f acc_o[2][4];
  float lsum[2][4];
#pragma unroll
  for (int i = 0; i < 2; i++) {
#pragma unroll
    for (int r = 0; r < 4; r++) lsum[i][r] = 0.f;
#pragma unroll
    for (int jd = 0; jd < 4; jd++) acc_o[i][jd] = zero;
  }

  v8bf qf[2][2];
#pragma unroll
  for (int i = 0; i < 2; i++) {
    int lq = qt * 128 + wid * 32 + i * 16 + l16;
#pragma unroll
    for (int kk = 0; kk < 2; kk++)
      qf[i][kk] = load8(qb + ((size_t)nh * LSEQ + lq) * 64 + kk * 32 + quad * 8);
  }

  int swl = l16 & 7;
  int srow = tid >> 3;
  int sseg0 = tid & 7;
  int lbase = (tid & 192) * 8;

  for (int s0 = 0; s0 < LSEQ; s0 += 64) {
#pragma unroll
    for (int p = 0; p < 2; p++) {
      int row = p * 32 + srow;
      int seg = sseg0 ^ (row & 7);
      gload16(khead + (size_t)(s0 + row) * 64 + seg * 8, &lK[p * 2048 + lbase]);
      gload16(vhead + (size_t)row * LSEQ + s0 + seg * 8, &lV[p * 2048 + lbase]);
    }
    __syncthreads();

    v4f sacc[2][4];
#pragma unroll
    for (int i = 0; i < 2; i++)
#pragma unroll
      for (int j = 0; j < 4; j++) sacc[i][j] = zero;
#pragma unroll
    for (int kk = 0; kk < 2; kk++) {
      v8bf kf[4];
#pragma unroll
      for (int j = 0; j < 4; j++) {
        int rl = j * 16 + l16;
        kf[j] = load8(&lK[((rl << 3) + (((kk << 2) + quad) ^ swl)) << 3]);
      }
#pragma unroll
      for (int i = 0; i < 2; i++)
#pragma unroll
        for (int j = 0; j < 4; j++)
          sacc[i][j] = mfma16(qf[i][kk], kf[j], sacc[i][j]);
    }

#pragma unroll
    for (int i = 0; i < 2; i++) {
#pragma unroll
      for (int r = 0; r < 4; r++) {
        float ps = 0.f;
#pragma unroll
        for (int j = 0; j < 4; j++) {
          float p = __expf(fminf(sacc[i][j][r], 60.f));
          ps += p;
          pl[wid * 32 + i * 16 + quad * 4 + r][j * 16 + l16] = f2bf(p);
        }
        lsum[i][r] += ps;
      }
    }

#pragma unroll
    for (int kk = 0; kk < 2; kk++) {
      v8bf pf[2], vf[4];
#pragma unroll
      for (int i = 0; i < 2; i++)
        pf[i] = load8(&pl[wid * 32 + i * 16 + l16][kk * 32 + quad * 8]);
#pragma unroll
      for (int jd = 0; jd < 4; jd++) {
        int dl = jd * 16 + l16;
        vf[jd] = load8(&lV[((dl << 3) + (((kk << 2) + quad) ^ swl)) << 3]);
      }
#pragma unroll
      for (int i = 0; i < 2; i++)
#pragma unroll
        for (int jd = 0; jd < 4; jd++)
          acc_o[i][jd] = mfma16(pf[i], vf[jd], acc_o[i][jd]);
    }
    __syncthreads();
  }

#pragma unroll
  for (int i = 0; i < 2; i++) {
#pragma unroll
    for (int r = 0; r < 4; r++) {
      float s = lsum[i][r];
#pragma unroll
      for (int off = 1; off < 16; off <<= 1) s += __shfl_xor(s, off);
      float inv = 1.0f / s;
      int lq = qt * 128 + wid * 32 + i * 16 + quad * 4 + r;
      size_t t = (size_t)lq * NBATCH + n;
#pragma unroll
      for (int jd = 0; jd < 4; jd++)
        o[t * EMB + h * 64 + jd * 16 + l16] = f2bf(acc_o[i][jd][r] * inv);
    }
  }
}

// ---------------- launcher ----------------
extern "C" void kernel_launch(void* const* d_in, const int* in_sizes, int n_in,
                              void* d_out, int out_size, void* d_ws,
                              size_t ws_size, hipStream_t stream) {
  const float* x = (const float*)d_in[0];
  const float* ln1_w = (const float*)d_in[1];
  const float* ln1_b = (const float*)d_in[2];
  const float* in_proj_w = (const float*)d_in[3];
  const float* in_proj_b = (const float*)d_in[4];
  const float* out_w = (const float*)d_in[5];
  const float* out_b = (const float*)d_in[6];
  const float* ln2_w = (const float*)d_in[7];
  const float* ln2_b = (const float*)d_in[8];
  const float* fc_w = (const float*)d_in[9];
  const float* fc_b = (const float*)d_in[10];
  const float* proj_w = (const float*)d_in[11];
  const float* proj_b = (const float*)d_in[12];
  float* out = (float*)d_out;

  char* ws = (char*)d_ws;
  // wbuf [0,8) ; y/o/h [8,40) ; qkv head-major [16,40) ; x2 bf16 [40,48) ;
  // z [48,56).  56 MB peak (known-good budget).
  u16* wbuf = (u16*)(ws + 0);
  u16* y = (u16*)(ws + 8388608);
  u16* qkvh = (u16*)(ws + 16777216);
  u16* o = (u16*)(ws + 8388608);
  u16* hbuf = (u16*)(ws + 8388608);
  u16* x2 = (u16*)(ws + 41943040);
  u16* z = (u16*)(ws + 50331648);

  u16* qb = qkvh;
  u16* kb = qkvh + 4194304;
  u16* vtb = qkvh + 8388608;

  // 1. ln1(x) -> y
  ln_kernel<1><<<TOK, 256, 0, stream>>>((const void*)x, ln1_w, ln1_b, y);
  // 2. qkv = y @ in_proj^T + b, head-major scatter (q scaled). Grid (16,12)
  //    = 192 blocks (shape-fixed; 75% machine).
  cvt_kernel<<<1536, 256, 0, stream>>>(in_proj_w, wbuf);
  gemm8_kernel<256, 256><<<dim3(16, 12), 512, 0, stream>>>(
      y, wbuf, in_proj_b, EMB, 3 * EMB, 4, qkvh, nullptr, nullptr);
  // 3. attention -> o
  flash_kernel<<<dim3(16, 32), 256, 0, stream>>>(qb, kb, vtb, o);
  // 4. x2 = bf16(x + o @ out_w^T + out_b). Small GEMM, unchanged.
  cvt_kernel<<<512, 256, 0, stream>>>(out_w, wbuf);
  gemm_db_kernel<64, 128><<<dim3(64, 8), 256, 0, stream>>>(
      o, wbuf, out_b, EMB, EMB, 1, x2, nullptr, x, nullptr);
  // 5. ln2(x2) -> z
  ln_kernel<0><<<TOK, 256, 0, stream>>>((const void*)x2, ln2_w, ln2_b, z);
  // 6. h = gelu_fast(z @ fc_w^T + fc_b). Grid (16,16) = 256 blocks (full).
  cvt_kernel<<<2048, 256, 0, stream>>>(fc_w, wbuf);
  gemm8_kernel<256, 256><<<dim3(16, 16), 512, 0, stream>>>(
      z, wbuf, fc_b, EMB, 4 * EMB, 2, hbuf, nullptr, nullptr);
  // 7. out = x2 + h @ proj_w^T + proj_b. BN=128 + split-K=2 -> grid
  //    (16,8,2) = 256 blocks = FULL machine (R6 ran 128 = half idle;
  //    per-block rate was already +64% vs R5). Chunk0 -> bf16 partial in
  //    z; chunk1 (+bias+x2) -> fp32 d_out; addred out += p0.
  cvt_kernel<<<2048, 256, 0, stream>>>(proj_w, wbuf);
  gemm8_kernel<256, 128><<<dim3(16, 8, 2), 512, 0, stream>>>(
      hbuf, wbuf, proj_b, 4 * EMB, EMB, 5, z, out, x2);
  addred_kernel<<<2048, 256, 0, stream>>>(out, z);
}

// Round 9
// 419.148 us; speedup vs baseline: 1.1133x; 1.0196x over previous
//
#include <hip/hip_runtime.h>
#include <hip/hip_bf16.h>

typedef unsigned short u16;
typedef float v4f __attribute__((ext_vector_type(4)));
typedef __bf16 v8bf __attribute__((ext_vector_type(8)));
typedef unsigned short v4u __attribute__((ext_vector_type(4)));
typedef unsigned short v8u __attribute__((ext_vector_type(8)));

#define EMB 1024
#define TOK 4096
#define LSEQ 2048
#define NBATCH 2
#define SCALING 0.015625f
#define LN_EPS 1e-5f

template <int V> struct ic { static constexpr int v = V; };

__device__ __forceinline__ float bf2f(u16 u) {
  unsigned int i = ((unsigned int)u) << 16;
  return __builtin_bit_cast(float, i);
}
__device__ __forceinline__ u16 f2bf(float f) {
  __hip_bfloat16 h = __float2bfloat16(f);  // RNE
  return __builtin_bit_cast(u16, h);
}
__device__ __forceinline__ v8bf load8(const u16* p) {
  return *reinterpret_cast<const v8bf*>(p);
}
__device__ __forceinline__ v4f mfma16(v8bf a, v8bf b, v4f c) {
  return __builtin_amdgcn_mfma_f32_16x16x32_bf16(a, b, c, 0, 0, 0);
}
// async global->LDS, 16B/lane; LDS dest = wave-uniform base + lane*16
__device__ __forceinline__ void gload16(const u16* g, u16* l) {
  __builtin_amdgcn_global_load_lds(
      (const __attribute__((address_space(1))) void*)g,
      (__attribute__((address_space(3))) void*)l, 16, 0, 0);
}
// counted vmcnt wait: allow N loads to remain in flight (T4). "memory"
// clobber also pins compiler ordering of LDS reads / gload_lds around it.
template <int N>
__device__ __forceinline__ void waitcnt_vm() {
  if constexpr (N == 0) asm volatile("s_waitcnt vmcnt(0)" ::: "memory");
  else if constexpr (N == 2) asm volatile("s_waitcnt vmcnt(2)" ::: "memory");
  else if constexpr (N == 3) asm volatile("s_waitcnt vmcnt(3)" ::: "memory");
  else if constexpr (N == 4) asm volatile("s_waitcnt vmcnt(4)" ::: "memory");
  else if constexpr (N == 6) asm volatile("s_waitcnt vmcnt(6)" ::: "memory");
  else if constexpr (N == 8) asm volatile("s_waitcnt vmcnt(8)" ::: "memory");
}
// fast GELU (tanh form, ~9 VALU ops, no divergence): max |err| ~3e-4
__device__ __forceinline__ float gelu_fast(float v) {
  float u = v * (0.7978845608f + 0.0356774081f * v * v);
  return v / (1.0f + __expf(-2.0f * u));
}

// ---------------- fp32 -> bf16 weight conversion -------------------------
__global__ __launch_bounds__(256) void cvt_kernel(
    const float* __restrict__ in, u16* __restrict__ out) {
  size_t i = ((size_t)blockIdx.x * 256 + threadIdx.x) * 8;
  v4f a = *reinterpret_cast<const v4f*>(in + i);
  v4f b = *reinterpret_cast<const v4f*>(in + i + 4);
  v8u r;
#pragma unroll
  for (int j = 0; j < 4; j++) { r[j] = f2bf(a[j]); r[4 + j] = f2bf(b[j]); }
  *reinterpret_cast<v8u*>(out + i) = r;
}

// ---------------- split-K reduce: out += p0(bf16) ------------------------
__global__ __launch_bounds__(256) void addred_kernel(
    float* __restrict__ out, const u16* __restrict__ p0) {
  size_t i = ((size_t)blockIdx.x * 256 + threadIdx.x) * 8;
  v4f a0 = *reinterpret_cast<const v4f*>(out + i);
  v4f a1 = *reinterpret_cast<const v4f*>(out + i + 4);
  v8u pp = *reinterpret_cast<const v8u*>(p0 + i);
#pragma unroll
  for (int j = 0; j < 4; j++) {
    a0[j] += bf2f(pp[j]);
    a1[j] += bf2f(pp[4 + j]);
  }
  *reinterpret_cast<v4f*>(out + i) = a0;
  *reinterpret_cast<v4f*>(out + i + 4) = a1;
}

// ---------------- LayerNorm: MODE 0 bf16-in, MODE 1 fp32-in -> bf16 out --
template <int MODE>
__global__ __launch_bounds__(256) void ln_kernel(
    const void* __restrict__ xin, const float* __restrict__ w,
    const float* __restrict__ b, u16* __restrict__ y) {
  int t = blockIdx.x, tid = threadIdx.x;
  float v[4];
  if (MODE == 0) {
    v4u raw = *reinterpret_cast<const v4u*>((const u16*)xin + (size_t)t * EMB + tid * 4);
#pragma unroll
    for (int j = 0; j < 4; j++) v[j] = bf2f(raw[j]);
  } else {
    v4f raw = *reinterpret_cast<const v4f*>((const float*)xin + (size_t)t * EMB + tid * 4);
#pragma unroll
    for (int j = 0; j < 4; j++) v[j] = raw[j];
  }
  float s = v[0] + v[1] + v[2] + v[3];
  float ss = v[0] * v[0] + v[1] * v[1] + v[2] * v[2] + v[3] * v[3];
#pragma unroll
  for (int off = 32; off >= 1; off >>= 1) {
    s += __shfl_xor(s, off);
    ss += __shfl_xor(ss, off);
  }
  __shared__ float sm[4], sq[4];
  if ((tid & 63) == 0) { sm[tid >> 6] = s; sq[tid >> 6] = ss; }
  __syncthreads();
  s = sm[0] + sm[1] + sm[2] + sm[3];
  ss = sq[0] + sq[1] + sq[2] + sq[3];
  float mu = s * (1.0f / EMB);
  float var = ss * (1.0f / EMB) - mu * mu;
  float rstd = rsqrtf(var + LN_EPS);
  v4f wv = *reinterpret_cast<const v4f*>(w + tid * 4);
  v4f bv = *reinterpret_cast<const v4f*>(b + tid * 4);
  v4u out;
#pragma unroll
  for (int j = 0; j < 4; j++) out[j] = f2bf((v[j] - mu) * rstd * wv[j] + bv[j]);
  *reinterpret_cast<v4u*>(y + (size_t)t * EMB + tid * 4) = out;
}

// ---------------- small GEMM engine (256 thr, <64,128>): out GEMM only ---
// mode 1: out_bf = bf16(res_f32 + v)
template <int BM, int BN>
__global__ __launch_bounds__(256) void gemm_db_kernel(
    const u16* __restrict__ A, const u16* __restrict__ W,
    const float* __restrict__ bias, int K, int Nout, int mode,
    u16* __restrict__ out_bf, float* __restrict__ out_f,
    const float* __restrict__ res_f32, const u16* __restrict__ res_bf) {
  constexpr int NJ = BM * BN / 4096;   // col fragments per wave
  constexpr int CWV = 4 / (BM / 64);   // col-waves
  __shared__ alignas(16) u16 lA[2][BM * 32];
  __shared__ alignas(16) u16 lB[2][BN * 32];

  int tid = threadIdx.x;
  int lane = tid & 63, wid = tid >> 6;
  int quad = lane >> 4, l16 = lane & 15;
  int row0 = blockIdx.x * BM;
  int col0 = blockIdx.y * BN;
  int rw = (wid / CWV) * 64;
  int cw = (wid % CWV) * (BN / CWV);

  v4f zero = {0.f, 0.f, 0.f, 0.f};
  v4f acc[4][NJ];
#pragma unroll
  for (int i = 0; i < 4; i++)
#pragma unroll
    for (int j = 0; j < NJ; j++) acc[i][j] = zero;

  int wbase8 = (tid & 192) * 8;

  auto stage = [&](int buf, int k0) {
    const u16* Ab = A + (size_t)row0 * K + k0;
    const u16* Wb = W + (size_t)col0 * K + k0;
#pragma unroll
    for (int n = 0; n < BM / 64; n++) {
      int slot = n * 256 + tid;
      int seg = slot / BM, r = slot & (BM - 1);
      gload16(Ab + (size_t)r * K + seg * 8, &lA[buf][n * 2048 + wbase8]);
    }
#pragma unroll
    for (int n = 0; n < BN / 64; n++) {
      int slot = n * 256 + tid;
      int seg = slot / BN, r = slot & (BN - 1);
      gload16(Wb + (size_t)r * K + seg * 8, &lB[buf][n * 2048 + wbase8]);
    }
  };

  stage(0, 0);
  int buf = 0;
  for (int k0 = 0; k0 < K; k0 += 32) {
    __syncthreads();
    if (k0 + 32 < K) stage(buf ^ 1, k0 + 32);

    v8bf af[4], bfr[NJ];
#pragma unroll
    for (int i = 0; i < 4; i++)
      af[i] = load8(&lA[buf][(quad * BM + rw + i * 16 + l16) * 8]);
#pragma unroll
    for (int j = 0; j < NJ; j++)
      bfr[j] = load8(&lB[buf][(quad * BN + cw + j * 16 + l16) * 8]);
#pragma unroll
    for (int i = 0; i < 4; i++)
#pragma unroll
      for (int j = 0; j < NJ; j++)
        acc[i][j] = mfma16(af[i], bfr[j], acc[i][j]);
    buf ^= 1;
  }

#pragma unroll
  for (int i = 0; i < 4; i++) {
    int rbase = row0 + rw + i * 16 + quad * 4;
#pragma unroll
    for (int j = 0; j < NJ; j++) {
      int c = col0 + cw + j * 16 + l16;
      float bv = bias[c];
#pragma unroll
      for (int r = 0; r < 4; r++) {
        int tok = rbase + r;
        float v = acc[i][j][r] + bv;
        size_t idx = (size_t)tok * Nout + c;
        if (mode == 1) {
          out_bf[idx] = f2bf(res_f32[idx] + v);
        } else if (mode == 3) {
          out_f[idx] = bf2f(res_bf[idx]) + v;
        }
      }
    }
  }
}

// ---------------- 8-phase GEMM engine (T3+T4+T5), BN in {128,256} --------
// R17 fixed the lB sizing typo; R8 verified: all gemm8 dispatches now
// < 79 µs (out of top-5). Schedule: per K-tile (BK=64) 4 phases
// {ds_read subtile || issue 1 group-stage -> BAR -> setprio(1) -> MFMA
// cluster -> setprio(0) -> counted vmcnt -> BAR}; never drain in-loop.
// Load counts LA=2, LB=BN/128; waits: prologue LA+LB, ph0 2LA, ph1 LA+LB,
// ph3 LA+LB. Rule-21 both-sides swizzle (seg ^= row&7).
// LDS: 2buf x 2grp x (BM*64 + BN*64) B = 128KB(BN=256)/96KB(BN=128).
// mode 2: out_bf = gelu_fast(v)   mode 4: qkv head-major scatter
// mode 5: split-K=2 over blockIdx.z (z0 -> bf16 raw partial, z1 -> fp32
//         v+bias+res_bf; addred adds).
template <int BM, int BN>
__global__ __launch_bounds__(512, 2) void gemm8_kernel(
    const u16* __restrict__ A, const u16* __restrict__ W,
    const float* __restrict__ bias, int K, int Nout, int mode,
    u16* __restrict__ out_bf, float* __restrict__ out_f,
    const u16* __restrict__ res_bf) {
  static_assert(BM == 256 && (BN == 128 || BN == 256), "geometry");
  constexpr int NJF = BN / 128;        // B col-fragments per wave per group
  constexpr int LB = BN / 128;         // gload16 per thread per B-group
  constexpr int H = BN / 8;            // B group sub-half width (cols)
  __shared__ alignas(16) u16 lA[2][2][8192];
  __shared__ alignas(16) u16 lB[2][2][BN * 32];  // BN*32 u16 = BN*64 B/group

  int tid = threadIdx.x;
  int lane = tid & 63, wid = tid >> 6;
  int quad = lane >> 4, l16 = lane & 15;
  int rwh = wid >> 2;            // wave row-half (rows rwh*128 ..)
  int cwq = wid & 3;             // wave col quarter (cols cwq*(BN/4) ..)
  int row0 = blockIdx.x * BM, col0 = blockIdx.y * BN;

  int kbeg = 0, kend = K;
  if (mode == 5) { int h = K >> 1; kbeg = blockIdx.z * h; kend = kbeg + h; }
  int nt = (kend - kbeg) >> 6;   // K-tiles of 64

  v4f zero = {0.f, 0.f, 0.f, 0.f};
  v4f acc[8][2 * NJF];
#pragma unroll
  for (int i = 0; i < 8; i++)
#pragma unroll
    for (int j = 0; j < 2 * NJF; j++) acc[i][j] = zero;

  int wslot = tid & 448;  // wid*64: wave-uniform LDS slot base

  // ---- staging: A group = 1024 slots of 16B (2/thread); B = 512*LB ----
  auto stA = [&](int buf, int g, int kt) {
    int koff = kbeg + kt * 64;
#pragma unroll
    for (int n = 0; n < 2; n++) {
      int p = n * 512 + tid;
      int ri = p >> 3, sp = p & 7;
      int row = ((ri >> 6) << 7) | (g << 6) | (ri & 63);
      int sl = sp ^ (ri & 7);
      gload16(A + (size_t)(row0 + row) * K + koff + sl * 8,
              &lA[buf][g][(n * 512 + wslot) * 8]);
    }
  };
  auto stB = [&](int buf, int g, int kt) {
    int koff = kbeg + kt * 64;
#pragma unroll
    for (int n = 0; n < LB; n++) {
      int p = n * 512 + tid;
      int ci = p >> 3, sp = p & 7;
      int col = (ci / H) * (2 * H) + g * H + (ci % H);
      int sl = sp ^ (ci & 7);
      gload16(W + (size_t)(col0 + col) * K + koff + sl * 8,
              &lB[buf][g][(n * 512 + wslot) * 8]);
    }
  };

  // ---- register subtile reads ----
  auto rdA = [&](v8bf (&af)[4][2], int buf, int g) {
#pragma unroll
    for (int i = 0; i < 4; i++) {
      int ri = (rwh << 6) + i * 16 + l16;
      int rs = ri * 8, rx = ri & 7;
#pragma unroll
      for (int kk = 0; kk < 2; kk++)
        af[i][kk] = load8(&lA[buf][g][(rs + ((kk * 4 + quad) ^ rx)) * 8]);
    }
  };
  auto rdB = [&](v8bf (&bf)[NJF][2], int buf, int g) {
#pragma unroll
    for (int j = 0; j < NJF; j++) {
      int ci = cwq * H + j * 16 + l16;
      int rs = ci * 8, rx = ci & 7;
#pragma unroll
      for (int kk = 0; kk < 2; kk++)
        bf[j][kk] = load8(&lB[buf][g][(rs + ((kk * 4 + quad) ^ rx)) * 8]);
    }
  };
  // ---- one C-quadrant x K=64 (static acc indices via ic<>) ----
  auto mm = [&](auto QA, auto QB, v8bf (&af)[4][2], v8bf (&bf)[NJF][2]) {
    constexpr int qa = decltype(QA)::v, qb = decltype(QB)::v;
#pragma unroll
    for (int i = 0; i < 4; i++)
#pragma unroll
      for (int j = 0; j < NJF; j++)
#pragma unroll
        for (int kk = 0; kk < 2; kk++)
          acc[qa * 4 + i][qb * NJF + j] =
              mfma16(af[i][kk], bf[j][kk], acc[qa * 4 + i][qb * NJF + j]);
  };

  v8bf af[4][2], b0[NJF][2], b1[NJF][2];

  // prologue: tile 0, stage order A0,B0,B1,A1 (matches wait schedule)
  stA(0, 0, 0); stB(0, 0, 0); stB(0, 1, 0); stA(0, 1, 0);
  waitcnt_vm<2 + LB>();            // A0(0), B0(0) landed
  __builtin_amdgcn_s_barrier();

  for (int t = 0; t < nt - 1; ++t) {
    int buf = t & 1, nb = buf ^ 1;
    // ph0: quadrant (0,0)
    rdA(af, buf, 0); rdB(b0, buf, 0);
    stA(nb, 0, t + 1);
    __builtin_amdgcn_s_barrier();
    __builtin_amdgcn_s_setprio(1);
    mm(ic<0>{}, ic<0>{}, af, b0);
    __builtin_amdgcn_s_setprio(0);
    waitcnt_vm<4>();               // B1(t) landed (leave A1 + A0')
    __builtin_amdgcn_s_barrier();
    // ph1: quadrant (0,1)
    rdB(b1, buf, 1);
    stB(nb, 0, t + 1);
    __builtin_amdgcn_s_barrier();
    __builtin_amdgcn_s_setprio(1);
    mm(ic<0>{}, ic<1>{}, af, b1);
    __builtin_amdgcn_s_setprio(0);
    waitcnt_vm<2 + LB>();          // A1(t) landed (leave A0' + B0')
    __builtin_amdgcn_s_barrier();
    // ph2: quadrant (1,1)
    rdA(af, buf, 1);
    stB(nb, 1, t + 1);
    __builtin_amdgcn_s_barrier();
    __builtin_amdgcn_s_setprio(1);
    mm(ic<1>{}, ic<1>{}, af, b1);
    __builtin_amdgcn_s_setprio(0);
    __builtin_amdgcn_s_barrier();
    // ph3: quadrant (1,0) — no reads
    stA(nb, 1, t + 1);
    __builtin_amdgcn_s_barrier();
    __builtin_amdgcn_s_setprio(1);
    mm(ic<1>{}, ic<0>{}, af, b0);
    __builtin_amdgcn_s_setprio(0);
    waitcnt_vm<2 + LB>();          // A0(t+1), B0(t+1) landed (leave B1'+A1')
    __builtin_amdgcn_s_barrier();
  }
  // peeled final tile: single drain
  waitcnt_vm<0>();
  __builtin_amdgcn_s_barrier();
  {
    int buf = (nt - 1) & 1;
    rdA(af, buf, 0); rdB(b0, buf, 0); rdB(b1, buf, 1);
    mm(ic<0>{}, ic<0>{}, af, b0);
    mm(ic<0>{}, ic<1>{}, af, b1);
    rdA(af, buf, 1);
    mm(ic<1>{}, ic<1>{}, af, b1);
    mm(ic<1>{}, ic<0>{}, af, b0);
  }

  // ---- epilogue ----
  int rw = rwh << 7;
  int cw = cwq * (BN / 4);
#pragma unroll
  for (int i = 0; i < 8; i++) {
    int rbase = row0 + rw + i * 16 + quad * 4;
#pragma unroll
    for (int j = 0; j < 2 * NJF; j++) {
      int c = col0 + cw + j * 16 + l16;
      float bv = bias[c];
#pragma unroll
      for (int r = 0; r < 4; r++) {
        int tok = rbase + r;
        float raw = acc[i][j][r];
        float v = raw + bv;
        if (mode == 4) {
          int region = c >> 10;  // 0=q,1=k,2=v
          int cc = c & 1023;
          int hh = cc >> 6, dd = cc & 63;
          int l = tok >> 1, nn = tok & 1;
          size_t hb = (size_t)(nn * 16 + hh);
          if (region == 0) {
            out_bf[(hb * LSEQ + l) * 64 + dd] = f2bf(v * SCALING);
          } else if (region == 1) {
            out_bf[4194304 + (hb * LSEQ + l) * 64 + dd] = f2bf(v);
          } else {
            out_bf[8388608 + (hb * 64 + dd) * LSEQ + l] = f2bf(v);
          }
        } else {
          size_t idx = (size_t)tok * Nout + c;
          if (mode == 2) {
            out_bf[idx] = f2bf(gelu_fast(v));
          } else {  // mode 5: split-K partials
            if (blockIdx.z == 0) {
              out_bf[idx] = f2bf(raw);                  // chunk-0 raw partial
            } else {
              out_f[idx] = v + bf2f(res_bf[idx]);       // chunk-1 + bias + x2
            }
          }
        }
      }
    }
  }
}

// ---------------- Flash attention (no-max softmax, swizzled LDS) ---------
// Inputs head-major: q,k (n,h,l,d) [q pre-scaled], vt (n,h,d,l).
// R18: R8 counters (VALUBusy 47.8% vs MfmaUtil 17.4%, occupancy 19% =
// 8 waves/CU) -> softmax VALU chain is the limiter and it's TLP-starved.
// Restructure 4 waves x 32 q-rows -> 8 waves x 16 q-rows (512 threads):
// 16 waves/CU fill the VALU dependency gaps and cover the per-tile
// vmcnt(0)+barrier staging drain. Same math, same pl layout, LDS 34KB
// (2 blocks/CU). Staging: 512 threads = one pass per K/V tile.
__global__ __launch_bounds__(512) void flash_kernel(
    const u16* __restrict__ qb, const u16* __restrict__ kb,
    const u16* __restrict__ vtb, u16* __restrict__ o) {
  int tid = threadIdx.x;
  int lane = tid & 63, wid = tid >> 6;   // 8 waves, 16 q-rows each
  int quad = lane >> 4, l16 = lane & 15;
  int qt = blockIdx.x;
  int nh = blockIdx.y;
  int n = nh >> 4, h = nh & 15;

  __shared__ alignas(16) u16 lK[4096];
  __shared__ alignas(16) u16 lV[4096];
  __shared__ alignas(16) u16 pl[128][72];

  const u16* khead = kb + (size_t)nh * (LSEQ * 64);
  const u16* vhead = vtb + (size_t)nh * (64 * LSEQ);

  v4f zero = {0.f, 0.f, 0.f, 0.f};
  v4f acc_o[4];
  float lsum[4];
#pragma unroll
  for (int r = 0; r < 4; r++) lsum[r] = 0.f;
#pragma unroll
  for (int jd = 0; jd < 4; jd++) acc_o[jd] = zero;

  v8bf qf[2];
  {
    int lq = qt * 128 + wid * 16 + l16;
#pragma unroll
    for (int kk = 0; kk < 2; kk++)
      qf[kk] = load8(qb + ((size_t)nh * LSEQ + lq) * 64 + kk * 32 + quad * 8);
  }

  int swl = l16 & 7;
  int srow = tid >> 3;      // 0..63: one slot per thread
  int sseg0 = tid & 7;
  int lbase = (tid & 448) * 8;  // wave-uniform slot base (u16 units)

  for (int s0 = 0; s0 < LSEQ; s0 += 64) {
    {
      int seg = sseg0 ^ (srow & 7);
      gload16(khead + (size_t)(s0 + srow) * 64 + seg * 8, &lK[lbase]);
      gload16(vhead + (size_t)srow * LSEQ + s0 + seg * 8, &lV[lbase]);
    }
    __syncthreads();

    v4f sacc[4];
#pragma unroll
    for (int j = 0; j < 4; j++) sacc[j] = zero;
#pragma unroll
    for (int kk = 0; kk < 2; kk++) {
      v8bf kf[4];
#pragma unroll
      for (int j = 0; j < 4; j++) {
        int rl = j * 16 + l16;
        kf[j] = load8(&lK[((rl << 3) + (((kk << 2) + quad) ^ swl)) << 3]);
      }
#pragma unroll
      for (int j = 0; j < 4; j++)
        sacc[j] = mfma16(qf[kk], kf[j], sacc[j]);
    }

#pragma unroll
    for (int r = 0; r < 4; r++) {
      float ps = 0.f;
#pragma unroll
      for (int j = 0; j < 4; j++) {
        float p = __expf(fminf(sacc[j][r], 60.f));
        ps += p;
        pl[wid * 16 + quad * 4 + r][j * 16 + l16] = f2bf(p);
      }
      lsum[r] += ps;
    }

#pragma unroll
    for (int kk = 0; kk < 2; kk++) {
      v8bf pf, vf[4];
      pf = load8(&pl[wid * 16 + l16][kk * 32 + quad * 8]);
#pragma unroll
      for (int jd = 0; jd < 4; jd++) {
        int dl = jd * 16 + l16;
        vf[jd] = load8(&lV[((dl << 3) + (((kk << 2) + quad) ^ swl)) << 3]);
      }
#pragma unroll
      for (int jd = 0; jd < 4; jd++)
        acc_o[jd] = mfma16(pf, vf[jd], acc_o[jd]);
    }
    __syncthreads();
  }

#pragma unroll
  for (int r = 0; r < 4; r++) {
    float s = lsum[r];
#pragma unroll
    for (int off = 1; off < 16; off <<= 1) s += __shfl_xor(s, off);
    float inv = 1.0f / s;
    int lq = qt * 128 + wid * 16 + quad * 4 + r;
    size_t t = (size_t)lq * NBATCH + n;
#pragma unroll
    for (int jd = 0; jd < 4; jd++)
      o[t * EMB + h * 64 + jd * 16 + l16] = f2bf(acc_o[jd][r] * inv);
  }
}

// ---------------- launcher ----------------
extern "C" void kernel_launch(void* const* d_in, const int* in_sizes, int n_in,
                              void* d_out, int out_size, void* d_ws,
                              size_t ws_size, hipStream_t stream) {
  const float* x = (const float*)d_in[0];
  const float* ln1_w = (const float*)d_in[1];
  const float* ln1_b = (const float*)d_in[2];
  const float* in_proj_w = (const float*)d_in[3];
  const float* in_proj_b = (const float*)d_in[4];
  const float* out_w = (const float*)d_in[5];
  const float* out_b = (const float*)d_in[6];
  const float* ln2_w = (const float*)d_in[7];
  const float* ln2_b = (const float*)d_in[8];
  const float* fc_w = (const float*)d_in[9];
  const float* fc_b = (const float*)d_in[10];
  const float* proj_w = (const float*)d_in[11];
  const float* proj_b = (const float*)d_in[12];
  float* out = (float*)d_out;

  char* ws = (char*)d_ws;
  // wbuf [0,8) ; y/o/h [8,40) ; qkv head-major [16,40) ; x2 bf16 [40,48) ;
  // z [48,56).  56 MB peak (known-good budget).
  u16* wbuf = (u16*)(ws + 0);
  u16* y = (u16*)(ws + 8388608);
  u16* qkvh = (u16*)(ws + 16777216);
  u16* o = (u16*)(ws + 8388608);
  u16* hbuf = (u16*)(ws + 8388608);
  u16* x2 = (u16*)(ws + 41943040);
  u16* z = (u16*)(ws + 50331648);

  u16* qb = qkvh;
  u16* kb = qkvh + 4194304;
  u16* vtb = qkvh + 8388608;

  // 1. ln1(x) -> y
  ln_kernel<1><<<TOK, 256, 0, stream>>>((const void*)x, ln1_w, ln1_b, y);
  // 2. qkv = y @ in_proj^T + b, head-major scatter (q scaled). Grid (16,12)
  //    = 192 blocks (shape-fixed; 75% machine).
  cvt_kernel<<<1536, 256, 0, stream>>>(in_proj_w, wbuf);
  gemm8_kernel<256, 256><<<dim3(16, 12), 512, 0, stream>>>(
      y, wbuf, in_proj_b, EMB, 3 * EMB, 4, qkvh, nullptr, nullptr);
  // 3. attention -> o. R18: 512-thread blocks, 8 waves x 16 q-rows ->
  //    16 waves/CU (was 8) to fill softmax VALU dependency gaps.
  flash_kernel<<<dim3(16, 32), 512, 0, stream>>>(qb, kb, vtb, o);
  // 4. x2 = bf16(x + o @ out_w^T + out_b). Small GEMM, unchanged.
  cvt_kernel<<<512, 256, 0, stream>>>(out_w, wbuf);
  gemm_db_kernel<64, 128><<<dim3(64, 8), 256, 0, stream>>>(
      o, wbuf, out_b, EMB, EMB, 1, x2, nullptr, x, nullptr);
  // 5. ln2(x2) -> z
  ln_kernel<0><<<TOK, 256, 0, stream>>>((const void*)x2, ln2_w, ln2_b, z);
  // 6. h = gelu_fast(z @ fc_w^T + fc_b). Grid (16,16) = 256 blocks (full).
  cvt_kernel<<<2048, 256, 0, stream>>>(fc_w, wbuf);
  gemm8_kernel<256, 256><<<dim3(16, 16), 512, 0, stream>>>(
      z, wbuf, fc_b, EMB, 4 * EMB, 2, hbuf, nullptr, nullptr);
  // 7. out = x2 + h @ proj_w^T + proj_b. BN=128 + split-K=2 -> grid
  //    (16,8,2) = 256 blocks = full machine. Chunk0 -> bf16 partial in
  //    z; chunk1 (+bias+x2) -> fp32 d_out; addred out += p0.
  cvt_kernel<<<2048, 256, 0, stream>>>(proj_w, wbuf);
  gemm8_kernel<256, 128><<<dim3(16, 8, 2), 512, 0, stream>>>(
      hbuf, wbuf, proj_b, 4 * EMB, EMB, 5, z, out, x2);
  addred_kernel<<<2048, 256, 0, stream>>>(out, z);
}

// Round 10
// 406.478 us; speedup vs baseline: 1.1480x; 1.0312x over previous
//
#include <hip/hip_runtime.h>
#include <hip/hip_bf16.h>

typedef unsigned short u16;
typedef float v4f __attribute__((ext_vector_type(4)));
typedef __bf16 v8bf __attribute__((ext_vector_type(8)));
typedef unsigned short v4u __attribute__((ext_vector_type(4)));
typedef unsigned short v8u __attribute__((ext_vector_type(8)));

#define EMB 1024
#define TOK 4096
#define LSEQ 2048
#define NBATCH 2
#define SCALING 0.015625f
#define LN_EPS 1e-5f

template <int V> struct ic { static constexpr int v = V; };

__device__ __forceinline__ float bf2f(u16 u) {
  unsigned int i = ((unsigned int)u) << 16;
  return __builtin_bit_cast(float, i);
}
__device__ __forceinline__ u16 f2bf(float f) {
  __hip_bfloat16 h = __float2bfloat16(f);  // RNE
  return __builtin_bit_cast(u16, h);
}
__device__ __forceinline__ v8bf load8(const u16* p) {
  return *reinterpret_cast<const v8bf*>(p);
}
__device__ __forceinline__ v4f mfma16(v8bf a, v8bf b, v4f c) {
  return __builtin_amdgcn_mfma_f32_16x16x32_bf16(a, b, c, 0, 0, 0);
}
// async global->LDS, 16B/lane; LDS dest = wave-uniform base + lane*16
__device__ __forceinline__ void gload16(const u16* g, u16* l) {
  __builtin_amdgcn_global_load_lds(
      (const __attribute__((address_space(1))) void*)g,
      (__attribute__((address_space(3))) void*)l, 16, 0, 0);
}
// counted vmcnt wait: allow N loads to remain in flight (T4). "memory"
// clobber also pins compiler ordering of LDS reads / gload_lds around it.
template <int N>
__device__ __forceinline__ void waitcnt_vm() {
  if constexpr (N == 0) asm volatile("s_waitcnt vmcnt(0)" ::: "memory");
  else if constexpr (N == 2) asm volatile("s_waitcnt vmcnt(2)" ::: "memory");
  else if constexpr (N == 3) asm volatile("s_waitcnt vmcnt(3)" ::: "memory");
  else if constexpr (N == 4) asm volatile("s_waitcnt vmcnt(4)" ::: "memory");
  else if constexpr (N == 6) asm volatile("s_waitcnt vmcnt(6)" ::: "memory");
  else if constexpr (N == 8) asm volatile("s_waitcnt vmcnt(8)" ::: "memory");
}
// fast GELU (tanh form, ~9 VALU ops, no divergence): max |err| ~3e-4
__device__ __forceinline__ float gelu_fast(float v) {
  float u = v * (0.7978845608f + 0.0356774081f * v * v);
  return v / (1.0f + __expf(-2.0f * u));
}

// ---------------- fp32 -> bf16 weight conversion -------------------------
__global__ __launch_bounds__(256) void cvt_kernel(
    const float* __restrict__ in, u16* __restrict__ out) {
  size_t i = ((size_t)blockIdx.x * 256 + threadIdx.x) * 8;
  v4f a = *reinterpret_cast<const v4f*>(in + i);
  v4f b = *reinterpret_cast<const v4f*>(in + i + 4);
  v8u r;
#pragma unroll
  for (int j = 0; j < 4; j++) { r[j] = f2bf(a[j]); r[4 + j] = f2bf(b[j]); }
  *reinterpret_cast<v8u*>(out + i) = r;
}

// ---------------- split-K reduce: out += p0(bf16) ------------------------
__global__ __launch_bounds__(256) void addred_kernel(
    float* __restrict__ out, const u16* __restrict__ p0) {
  size_t i = ((size_t)blockIdx.x * 256 + threadIdx.x) * 8;
  v4f a0 = *reinterpret_cast<const v4f*>(out + i);
  v4f a1 = *reinterpret_cast<const v4f*>(out + i + 4);
  v8u pp = *reinterpret_cast<const v8u*>(p0 + i);
#pragma unroll
  for (int j = 0; j < 4; j++) {
    a0[j] += bf2f(pp[j]);
    a1[j] += bf2f(pp[4 + j]);
  }
  *reinterpret_cast<v4f*>(out + i) = a0;
  *reinterpret_cast<v4f*>(out + i + 4) = a1;
}

// ---------------- LayerNorm: MODE 0 bf16-in, MODE 1 fp32-in -> bf16 out --
template <int MODE>
__global__ __launch_bounds__(256) void ln_kernel(
    const void* __restrict__ xin, const float* __restrict__ w,
    const float* __restrict__ b, u16* __restrict__ y) {
  int t = blockIdx.x, tid = threadIdx.x;
  float v[4];
  if (MODE == 0) {
    v4u raw = *reinterpret_cast<const v4u*>((const u16*)xin + (size_t)t * EMB + tid * 4);
#pragma unroll
    for (int j = 0; j < 4; j++) v[j] = bf2f(raw[j]);
  } else {
    v4f raw = *reinterpret_cast<const v4f*>((const float*)xin + (size_t)t * EMB + tid * 4);
#pragma unroll
    for (int j = 0; j < 4; j++) v[j] = raw[j];
  }
  float s = v[0] + v[1] + v[2] + v[3];
  float ss = v[0] * v[0] + v[1] * v[1] + v[2] * v[2] + v[3] * v[3];
#pragma unroll
  for (int off = 32; off >= 1; off >>= 1) {
    s += __shfl_xor(s, off);
    ss += __shfl_xor(ss, off);
  }
  __shared__ float sm[4], sq[4];
  if ((tid & 63) == 0) { sm[tid >> 6] = s; sq[tid >> 6] = ss; }
  __syncthreads();
  s = sm[0] + sm[1] + sm[2] + sm[3];
  ss = sq[0] + sq[1] + sq[2] + sq[3];
  float mu = s * (1.0f / EMB);
  float var = ss * (1.0f / EMB) - mu * mu;
  float rstd = rsqrtf(var + LN_EPS);
  v4f wv = *reinterpret_cast<const v4f*>(w + tid * 4);
  v4f bv = *reinterpret_cast<const v4f*>(b + tid * 4);
  v4u out;
#pragma unroll
  for (int j = 0; j < 4; j++) out[j] = f2bf((v[j] - mu) * rstd * wv[j] + bv[j]);
  *reinterpret_cast<v4u*>(y + (size_t)t * EMB + tid * 4) = out;
}

// ---------------- small GEMM engine (256 thr, <64,128>): out GEMM only ---
// R19: coalesced [row][seg^swz] staging (R5's proven +36% on this engine;
// was left on the scattered control layout since R4). Lanes 0..3 read one
// 64B line; read-side swizzle quad ^ ((row>>1)&3) keeps bank conflicts at
// 2-way (free). mode 1: out_bf = bf16(res_f32 + v)
template <int BM, int BN>
__global__ __launch_bounds__(256) void gemm_db_kernel(
    const u16* __restrict__ A, const u16* __restrict__ W,
    const float* __restrict__ bias, int K, int Nout, int mode,
    u16* __restrict__ out_bf, float* __restrict__ out_f,
    const float* __restrict__ res_f32, const u16* __restrict__ res_bf) {
  constexpr int NJ = BM * BN / 4096;   // col fragments per wave
  constexpr int CWV = 4 / (BM / 64);   // col-waves
  __shared__ alignas(16) u16 lA[2][BM * 32];  // [buf][row][phys_seg][8]
  __shared__ alignas(16) u16 lB[2][BN * 32];

  int tid = threadIdx.x;
  int lane = tid & 63, wid = tid >> 6;
  int quad = lane >> 4, l16 = lane & 15;
  int row0 = blockIdx.x * BM;
  int col0 = blockIdx.y * BN;
  int rw = (wid / CWV) * 64;
  int cw = (wid % CWV) * (BN / CWV);

  v4f zero = {0.f, 0.f, 0.f, 0.f};
  v4f acc[4][NJ];
#pragma unroll
  for (int i = 0; i < 4; i++)
#pragma unroll
    for (int j = 0; j < NJ; j++) acc[i][j] = zero;

  int wbase8 = (tid & 192) * 8;

  auto stage = [&](int buf, int k0) {
    const u16* Ab = A + (size_t)row0 * K + k0;
    const u16* Wb = W + (size_t)col0 * K + k0;
#pragma unroll
    for (int n = 0; n < BM / 64; n++) {
      int p = n * 256 + tid;
      int r = p >> 2, sp = p & 3;
      int sl = sp ^ ((r >> 1) & 3);
      gload16(Ab + (size_t)r * K + sl * 8, &lA[buf][n * 2048 + wbase8]);
    }
#pragma unroll
    for (int n = 0; n < BN / 64; n++) {
      int p = n * 256 + tid;
      int r = p >> 2, sp = p & 3;
      int sl = sp ^ ((r >> 1) & 3);
      gload16(Wb + (size_t)r * K + sl * 8, &lB[buf][n * 2048 + wbase8]);
    }
  };

  stage(0, 0);
  int buf = 0;
  for (int k0 = 0; k0 < K; k0 += 32) {
    __syncthreads();
    if (k0 + 32 < K) stage(buf ^ 1, k0 + 32);

    v8bf af[4], bfr[NJ];
#pragma unroll
    for (int i = 0; i < 4; i++) {
      int ra = rw + i * 16 + l16;
      af[i] = load8(&lA[buf][((ra << 2) + (quad ^ ((ra >> 1) & 3))) << 3]);
    }
#pragma unroll
    for (int j = 0; j < NJ; j++) {
      int rb = cw + j * 16 + l16;
      bfr[j] = load8(&lB[buf][((rb << 2) + (quad ^ ((rb >> 1) & 3))) << 3]);
    }
#pragma unroll
    for (int i = 0; i < 4; i++)
#pragma unroll
      for (int j = 0; j < NJ; j++)
        acc[i][j] = mfma16(af[i], bfr[j], acc[i][j]);
    buf ^= 1;
  }

#pragma unroll
  for (int i = 0; i < 4; i++) {
    int rbase = row0 + rw + i * 16 + quad * 4;
#pragma unroll
    for (int j = 0; j < NJ; j++) {
      int c = col0 + cw + j * 16 + l16;
      float bv = bias[c];
#pragma unroll
      for (int r = 0; r < 4; r++) {
        int tok = rbase + r;
        float v = acc[i][j][r] + bv;
        size_t idx = (size_t)tok * Nout + c;
        if (mode == 1) {
          out_bf[idx] = f2bf(res_f32[idx] + v);
        } else if (mode == 3) {
          out_f[idx] = bf2f(res_bf[idx]) + v;
        }
      }
    }
  }
}

// ---------------- 8-phase GEMM engine (T3+T4+T5), BN in {128,256} --------
// R17 fixed the lB sizing typo; R8 verified: all gemm8 dispatches now
// < 79 µs (out of top-5). Schedule: per K-tile (BK=64) 4 phases
// {ds_read subtile || issue 1 group-stage -> BAR -> setprio(1) -> MFMA
// cluster -> setprio(0) -> counted vmcnt -> BAR}; never drain in-loop.
// Load counts LA=2, LB=BN/128; waits: prologue LA+LB, ph0 2LA, ph1 LA+LB,
// ph3 LA+LB. Rule-21 both-sides swizzle (seg ^= row&7).
// LDS: 2buf x 2grp x (BM*64 + BN*64) B = 128KB(BN=256)/96KB(BN=128).
// mode 2: out_bf = gelu_fast(v)   mode 4: qkv head-major scatter
// mode 5: split-K=2 over blockIdx.z (z0 -> bf16 raw partial, z1 -> fp32
//         v+bias+res_bf; addred adds).
template <int BM, int BN>
__global__ __launch_bounds__(512, 2) void gemm8_kernel(
    const u16* __restrict__ A, const u16* __restrict__ W,
    const float* __restrict__ bias, int K, int Nout, int mode,
    u16* __restrict__ out_bf, float* __restrict__ out_f,
    const u16* __restrict__ res_bf) {
  static_assert(BM == 256 && (BN == 128 || BN == 256), "geometry");
  constexpr int NJF = BN / 128;        // B col-fragments per wave per group
  constexpr int LB = BN / 128;         // gload16 per thread per B-group
  constexpr int H = BN / 8;            // B group sub-half width (cols)
  __shared__ alignas(16) u16 lA[2][2][8192];
  __shared__ alignas(16) u16 lB[2][2][BN * 32];  // BN*32 u16 = BN*64 B/group

  int tid = threadIdx.x;
  int lane = tid & 63, wid = tid >> 6;
  int quad = lane >> 4, l16 = lane & 15;
  int rwh = wid >> 2;            // wave row-half (rows rwh*128 ..)
  int cwq = wid & 3;             // wave col quarter (cols cwq*(BN/4) ..)
  int row0 = blockIdx.x * BM, col0 = blockIdx.y * BN;

  int kbeg = 0, kend = K;
  if (mode == 5) { int h = K >> 1; kbeg = blockIdx.z * h; kend = kbeg + h; }
  int nt = (kend - kbeg) >> 6;   // K-tiles of 64

  v4f zero = {0.f, 0.f, 0.f, 0.f};
  v4f acc[8][2 * NJF];
#pragma unroll
  for (int i = 0; i < 8; i++)
#pragma unroll
    for (int j = 0; j < 2 * NJF; j++) acc[i][j] = zero;

  int wslot = tid & 448;  // wid*64: wave-uniform LDS slot base

  // ---- staging: A group = 1024 slots of 16B (2/thread); B = 512*LB ----
  auto stA = [&](int buf, int g, int kt) {
    int koff = kbeg + kt * 64;
#pragma unroll
    for (int n = 0; n < 2; n++) {
      int p = n * 512 + tid;
      int ri = p >> 3, sp = p & 7;
      int row = ((ri >> 6) << 7) | (g << 6) | (ri & 63);
      int sl = sp ^ (ri & 7);
      gload16(A + (size_t)(row0 + row) * K + koff + sl * 8,
              &lA[buf][g][(n * 512 + wslot) * 8]);
    }
  };
  auto stB = [&](int buf, int g, int kt) {
    int koff = kbeg + kt * 64;
#pragma unroll
    for (int n = 0; n < LB; n++) {
      int p = n * 512 + tid;
      int ci = p >> 3, sp = p & 7;
      int col = (ci / H) * (2 * H) + g * H + (ci % H);
      int sl = sp ^ (ci & 7);
      gload16(W + (size_t)(col0 + col) * K + koff + sl * 8,
              &lB[buf][g][(n * 512 + wslot) * 8]);
    }
  };

  // ---- register subtile reads ----
  auto rdA = [&](v8bf (&af)[4][2], int buf, int g) {
#pragma unroll
    for (int i = 0; i < 4; i++) {
      int ri = (rwh << 6) + i * 16 + l16;
      int rs = ri * 8, rx = ri & 7;
#pragma unroll
      for (int kk = 0; kk < 2; kk++)
        af[i][kk] = load8(&lA[buf][g][(rs + ((kk * 4 + quad) ^ rx)) * 8]);
    }
  };
  auto rdB = [&](v8bf (&bf)[NJF][2], int buf, int g) {
#pragma unroll
    for (int j = 0; j < NJF; j++) {
      int ci = cwq * H + j * 16 + l16;
      int rs = ci * 8, rx = ci & 7;
#pragma unroll
      for (int kk = 0; kk < 2; kk++)
        bf[j][kk] = load8(&lB[buf][g][(rs + ((kk * 4 + quad) ^ rx)) * 8]);
    }
  };
  // ---- one C-quadrant x K=64 (static acc indices via ic<>) ----
  auto mm = [&](auto QA, auto QB, v8bf (&af)[4][2], v8bf (&bf)[NJF][2]) {
    constexpr int qa = decltype(QA)::v, qb = decltype(QB)::v;
#pragma unroll
    for (int i = 0; i < 4; i++)
#pragma unroll
      for (int j = 0; j < NJF; j++)
#pragma unroll
        for (int kk = 0; kk < 2; kk++)
          acc[qa * 4 + i][qb * NJF + j] =
              mfma16(af[i][kk], bf[j][kk], acc[qa * 4 + i][qb * NJF + j]);
  };

  v8bf af[4][2], b0[NJF][2], b1[NJF][2];

  // prologue: tile 0, stage order A0,B0,B1,A1 (matches wait schedule)
  stA(0, 0, 0); stB(0, 0, 0); stB(0, 1, 0); stA(0, 1, 0);
  waitcnt_vm<2 + LB>();            // A0(0), B0(0) landed
  __builtin_amdgcn_s_barrier();

  for (int t = 0; t < nt - 1; ++t) {
    int buf = t & 1, nb = buf ^ 1;
    // ph0: quadrant (0,0)
    rdA(af, buf, 0); rdB(b0, buf, 0);
    stA(nb, 0, t + 1);
    __builtin_amdgcn_s_barrier();
    __builtin_amdgcn_s_setprio(1);
    mm(ic<0>{}, ic<0>{}, af, b0);
    __builtin_amdgcn_s_setprio(0);
    waitcnt_vm<4>();               // B1(t) landed (leave A1 + A0')
    __builtin_amdgcn_s_barrier();
    // ph1: quadrant (0,1)
    rdB(b1, buf, 1);
    stB(nb, 0, t + 1);
    __builtin_amdgcn_s_barrier();
    __builtin_amdgcn_s_setprio(1);
    mm(ic<0>{}, ic<1>{}, af, b1);
    __builtin_amdgcn_s_setprio(0);
    waitcnt_vm<2 + LB>();          // A1(t) landed (leave A0' + B0')
    __builtin_amdgcn_s_barrier();
    // ph2: quadrant (1,1)
    rdA(af, buf, 1);
    stB(nb, 1, t + 1);
    __builtin_amdgcn_s_barrier();
    __builtin_amdgcn_s_setprio(1);
    mm(ic<1>{}, ic<1>{}, af, b1);
    __builtin_amdgcn_s_setprio(0);
    __builtin_amdgcn_s_barrier();
    // ph3: quadrant (1,0) — no reads
    stA(nb, 1, t + 1);
    __builtin_amdgcn_s_barrier();
    __builtin_amdgcn_s_setprio(1);
    mm(ic<1>{}, ic<0>{}, af, b0);
    __builtin_amdgcn_s_setprio(0);
    waitcnt_vm<2 + LB>();          // A0(t+1), B0(t+1) landed (leave B1'+A1')
    __builtin_amdgcn_s_barrier();
  }
  // peeled final tile: single drain
  waitcnt_vm<0>();
  __builtin_amdgcn_s_barrier();
  {
    int buf = (nt - 1) & 1;
    rdA(af, buf, 0); rdB(b0, buf, 0); rdB(b1, buf, 1);
    mm(ic<0>{}, ic<0>{}, af, b0);
    mm(ic<0>{}, ic<1>{}, af, b1);
    rdA(af, buf, 1);
    mm(ic<1>{}, ic<1>{}, af, b1);
    mm(ic<1>{}, ic<0>{}, af, b0);
  }

  // ---- epilogue ----
  int rw = rwh << 7;
  int cw = cwq * (BN / 4);
#pragma unroll
  for (int i = 0; i < 8; i++) {
    int rbase = row0 + rw + i * 16 + quad * 4;
#pragma unroll
    for (int j = 0; j < 2 * NJF; j++) {
      int c = col0 + cw + j * 16 + l16;
      float bv = bias[c];
#pragma unroll
      for (int r = 0; r < 4; r++) {
        int tok = rbase + r;
        float raw = acc[i][j][r];
        float v = raw + bv;
        if (mode == 4) {
          int region = c >> 10;  // 0=q,1=k,2=v
          int cc = c & 1023;
          int hh = cc >> 6, dd = cc & 63;
          int l = tok >> 1, nn = tok & 1;
          size_t hb = (size_t)(nn * 16 + hh);
          if (region == 0) {
            out_bf[(hb * LSEQ + l) * 64 + dd] = f2bf(v * SCALING);
          } else if (region == 1) {
            out_bf[4194304 + (hb * LSEQ + l) * 64 + dd] = f2bf(v);
          } else {
            out_bf[8388608 + (hb * 64 + dd) * LSEQ + l] = f2bf(v);
          }
        } else {
          size_t idx = (size_t)tok * Nout + c;
          if (mode == 2) {
            out_bf[idx] = f2bf(gelu_fast(v));
          } else {  // mode 5: split-K partials
            if (blockIdx.z == 0) {
              out_bf[idx] = f2bf(raw);                  // chunk-0 raw partial
            } else {
              out_f[idx] = v + bf2f(res_bf[idx]);       // chunk-1 + bias + x2
            }
          }
        }
      }
    }
  }
}

// ---------------- Flash attention (no-max softmax, swizzled LDS) ---------
// Inputs head-major: q,k (n,h,l,d) [q pre-scaled], vt (n,h,d,l).
// R18: 8 waves x 16 q-rows, 512 thr -> 16 waves/CU (79->69 µs).
// R19: R9 counters (VALU 42%, Mfma 20%, both idle) -> the per-tile
// __syncthreads forced a vmcnt(0) drain of the K/V staging, 2x per tile,
// 32 tiles. Double-buffer K/V + counted vmcnt + raw barriers (T3/T4-lite):
// issue tile t+1's loads, vmcnt(2) (t landed, t+1 in flight), barrier,
// compute, barrier. ds_read results all consumed by MFMA before trailing
// barrier -> overwrite race-free; pl is wave-private. LDS 50KB, 2 blk/CU.
__global__ __launch_bounds__(512) void flash_kernel(
    const u16* __restrict__ qb, const u16* __restrict__ kb,
    const u16* __restrict__ vtb, u16* __restrict__ o) {
  int tid = threadIdx.x;
  int lane = tid & 63, wid = tid >> 6;   // 8 waves, 16 q-rows each
  int quad = lane >> 4, l16 = lane & 15;
  int qt = blockIdx.x;
  int nh = blockIdx.y;
  int n = nh >> 4, h = nh & 15;

  __shared__ alignas(16) u16 lK[2][4096];
  __shared__ alignas(16) u16 lV[2][4096];
  __shared__ alignas(16) u16 pl[128][72];

  const u16* khead = kb + (size_t)nh * (LSEQ * 64);
  const u16* vhead = vtb + (size_t)nh * (64 * LSEQ);

  v4f zero = {0.f, 0.f, 0.f, 0.f};
  v4f acc_o[4];
  float lsum[4];
#pragma unroll
  for (int r = 0; r < 4; r++) lsum[r] = 0.f;
#pragma unroll
  for (int jd = 0; jd < 4; jd++) acc_o[jd] = zero;

  v8bf qf[2];
  {
    int lq = qt * 128 + wid * 16 + l16;
#pragma unroll
    for (int kk = 0; kk < 2; kk++)
      qf[kk] = load8(qb + ((size_t)nh * LSEQ + lq) * 64 + kk * 32 + quad * 8);
  }

  int swl = l16 & 7;
  int srow = tid >> 3;      // 0..63: one slot per thread
  int sseg0 = tid & 7;
  int lbase = (tid & 448) * 8;  // wave-uniform slot base (u16 units)
  int sseg = sseg0 ^ (srow & 7);

  // prologue: stage tile 0 into buf 0
  gload16(khead + (size_t)srow * 64 + sseg * 8, &lK[0][lbase]);
  gload16(vhead + (size_t)srow * LSEQ + 0 + sseg * 8, &lV[0][lbase]);

  int buf = 0;
  for (int s0 = 0; s0 < LSEQ; s0 += 64) {
    if (s0 + 64 < LSEQ) {
      // issue next tile's loads into buf^1, then wait for current (leave 2)
      gload16(khead + (size_t)(s0 + 64 + srow) * 64 + sseg * 8,
              &lK[buf ^ 1][lbase]);
      gload16(vhead + (size_t)srow * LSEQ + (s0 + 64) + sseg * 8,
              &lV[buf ^ 1][lbase]);
      waitcnt_vm<2>();
    } else {
      waitcnt_vm<0>();
    }
    __builtin_amdgcn_s_barrier();

    v4f sacc[4];
#pragma unroll
    for (int j = 0; j < 4; j++) sacc[j] = zero;
#pragma unroll
    for (int kk = 0; kk < 2; kk++) {
      v8bf kf[4];
#pragma unroll
      for (int j = 0; j < 4; j++) {
        int rl = j * 16 + l16;
        kf[j] = load8(&lK[buf][((rl << 3) + (((kk << 2) + quad) ^ swl)) << 3]);
      }
#pragma unroll
      for (int j = 0; j < 4; j++)
        sacc[j] = mfma16(qf[kk], kf[j], sacc[j]);
    }

#pragma unroll
    for (int r = 0; r < 4; r++) {
      float ps = 0.f;
#pragma unroll
      for (int j = 0; j < 4; j++) {
        float p = __expf(fminf(sacc[j][r], 60.f));
        ps += p;
        pl[wid * 16 + quad * 4 + r][j * 16 + l16] = f2bf(p);
      }
      lsum[r] += ps;
    }

#pragma unroll
    for (int kk = 0; kk < 2; kk++) {
      v8bf pf, vf[4];
      pf = load8(&pl[wid * 16 + l16][kk * 32 + quad * 8]);
#pragma unroll
      for (int jd = 0; jd < 4; jd++) {
        int dl = jd * 16 + l16;
        vf[jd] = load8(&lV[buf][((dl << 3) + (((kk << 2) + quad) ^ swl)) << 3]);
      }
#pragma unroll
      for (int jd = 0; jd < 4; jd++)
        acc_o[jd] = mfma16(pf, vf[jd], acc_o[jd]);
    }
    __builtin_amdgcn_s_barrier();
    buf ^= 1;
  }

#pragma unroll
  for (int r = 0; r < 4; r++) {
    float s = lsum[r];
#pragma unroll
    for (int off = 1; off < 16; off <<= 1) s += __shfl_xor(s, off);
    float inv = 1.0f / s;
    int lq = qt * 128 + wid * 16 + quad * 4 + r;
    size_t t = (size_t)lq * NBATCH + n;
#pragma unroll
    for (int jd = 0; jd < 4; jd++)
      o[t * EMB + h * 64 + jd * 16 + l16] = f2bf(acc_o[jd][r] * inv);
  }
}

// ---------------- launcher ----------------
extern "C" void kernel_launch(void* const* d_in, const int* in_sizes, int n_in,
                              void* d_out, int out_size, void* d_ws,
                              size_t ws_size, hipStream_t stream) {
  const float* x = (const float*)d_in[0];
  const float* ln1_w = (const float*)d_in[1];
  const float* ln1_b = (const float*)d_in[2];
  const float* in_proj_w = (const float*)d_in[3];
  const float* in_proj_b = (const float*)d_in[4];
  const float* out_w = (const float*)d_in[5];
  const float* out_b = (const float*)d_in[6];
  const float* ln2_w = (const float*)d_in[7];
  const float* ln2_b = (const float*)d_in[8];
  const float* fc_w = (const float*)d_in[9];
  const float* fc_b = (const float*)d_in[10];
  const float* proj_w = (const float*)d_in[11];
  const float* proj_b = (const float*)d_in[12];
  float* out = (float*)d_out;

  char* ws = (char*)d_ws;
  // wbuf [0,8) ; y/o/h [8,40) ; qkv head-major [16,40) ; x2 bf16 [40,48) ;
  // z [48,56).  56 MB peak (known-good budget).
  u16* wbuf = (u16*)(ws + 0);
  u16* y = (u16*)(ws + 8388608);
  u16* qkvh = (u16*)(ws + 16777216);
  u16* o = (u16*)(ws + 8388608);
  u16* hbuf = (u16*)(ws + 8388608);
  u16* x2 = (u16*)(ws + 41943040);
  u16* z = (u16*)(ws + 50331648);

  u16* qb = qkvh;
  u16* kb = qkvh + 4194304;
  u16* vtb = qkvh + 8388608;

  // 1. ln1(x) -> y
  ln_kernel<1><<<TOK, 256, 0, stream>>>((const void*)x, ln1_w, ln1_b, y);
  // 2. qkv = y @ in_proj^T + b, head-major scatter (q scaled). Grid (16,12)
  //    = 192 blocks (shape-fixed; 75% machine).
  cvt_kernel<<<1536, 256, 0, stream>>>(in_proj_w, wbuf);
  gemm8_kernel<256, 256><<<dim3(16, 12), 512, 0, stream>>>(
      y, wbuf, in_proj_b, EMB, 3 * EMB, 4, qkvh, nullptr, nullptr);
  // 3. attention -> o. R19: K/V double-buffer + counted vmcnt.
  flash_kernel<<<dim3(16, 32), 512, 0, stream>>>(qb, kb, vtb, o);
  // 4. x2 = bf16(x + o @ out_w^T + out_b). R19: coalesced staging.
  cvt_kernel<<<512, 256, 0, stream>>>(out_w, wbuf);
  gemm_db_kernel<64, 128><<<dim3(64, 8), 256, 0, stream>>>(
      o, wbuf, out_b, EMB, EMB, 1, x2, nullptr, x, nullptr);
  // 5. ln2(x2) -> z
  ln_kernel<0><<<TOK, 256, 0, stream>>>((const void*)x2, ln2_w, ln2_b, z);
  // 6. h = gelu_fast(z @ fc_w^T + fc_b). Grid (16,16) = 256 blocks (full).
  cvt_kernel<<<2048, 256, 0, stream>>>(fc_w, wbuf);
  gemm8_kernel<256, 256><<<dim3(16, 16), 512, 0, stream>>>(
      z, wbuf, fc_b, EMB, 4 * EMB, 2, hbuf, nullptr, nullptr);
  // 7. out = x2 + h @ proj_w^T + proj_b. BN=128 + split-K=2 -> grid
  //    (16,8,2) = 256 blocks = full machine. Chunk0 -> bf16 partial in
  //    z; chunk1 (+bias+x2) -> fp32 d_out; addred out += p0.
  cvt_kernel<<<2048, 256, 0, stream>>>(proj_w, wbuf);
  gemm8_kernel<256, 128><<<dim3(16, 8, 2), 512, 0, stream>>>(
      hbuf, wbuf, proj_b, 4 * EMB, EMB, 5, z, out, x2);
  addred_kernel<<<2048, 256, 0, stream>>>(out, z);
}